// Round 7
// baseline (690.061 us; speedup 1.0000x reference)
//
#include <hip/hip_runtime.h>
#include <math.h>

#define H 6
#define DH 64
#define D 384
#define L 16
#define WSZ ((size_t)(D) * (D))
#define RSZ ((size_t)(H) * (DH) * (DH))

typedef __attribute__((ext_vector_type(8))) short short8;
typedef __attribute__((ext_vector_type(4))) float f32x4;
typedef unsigned int uint_;

__device__ __forceinline__ float bf2f(unsigned short u) {
  union { unsigned int i; float f; } x; x.i = ((unsigned int)u) << 16; return x.f;
}
__device__ __forceinline__ unsigned short f2bf(float f) {
  unsigned int x = __float_as_uint(f);
  x = x + 0x7fffu + ((x >> 16) & 1u);
  return (unsigned short)(x >> 16);
}
__device__ __forceinline__ float blo(unsigned int u) { return __uint_as_float(u << 16); }
__device__ __forceinline__ float bhi(unsigned int u) { return __uint_as_float(u & 0xffff0000u); }
__device__ __forceinline__ float geluf(float x) {
  return 0.5f * x * (1.0f + erff(x * 0.70710678118654752f));
}

__global__ void zero_int_kernel(int* p, long n) {
  long i = (long)blockIdx.x * blockDim.x + threadIdx.x;
  long stride = (long)gridDim.x * blockDim.x;
  for (; i < n; i += stride) p[i] = 0;
}

// masked mean pool over L tokens then L2 normalize -> bf16. one block per node (M then C).
// float4 loads: thread t handles channel-quad c4=t%96 over rows rg, rg+4, rg+8, rg+12 (rg=t/96).
__global__ void pool_norm_kernel(const float* __restrict__ tokM, const int* __restrict__ idsM,
                                 unsigned short* __restrict__ outM, int NM,
                                 const float* __restrict__ tokC, const int* __restrict__ idsC,
                                 unsigned short* __restrict__ outC) {
  int n = blockIdx.x;
  const float* tok; const int* ids; unsigned short* out;
  if (n < NM) { tok = tokM; ids = idsM; out = outM; }
  else { n -= NM; tok = tokC; ids = idsC; out = outC; }
  int t = threadIdx.x;
  int rg = t / 96, c4 = t % 96;
  const float4* tp = (const float4*)(tok + (size_t)n * L * D);
  const int* ip = ids + (size_t)n * L;
  int cnt = 0;
#pragma unroll
  for (int l = 0; l < L; ++l) cnt += (ip[l] > 0);
  float4 s = {0.f, 0.f, 0.f, 0.f};
#pragma unroll
  for (int li = 0; li < 4; ++li) {
    int l = rg + li * 4;
    if (ip[l] > 0) {
      float4 v = tp[l * 96 + c4];
      s.x += v.x; s.y += v.y; s.z += v.z; s.w += v.w;
    }
  }
  __shared__ float4 part[4][96];
  part[rg][c4] = s;
  __syncthreads();
  float4 m4 = {0.f, 0.f, 0.f, 0.f};
  float dot = 0.f;
  float inv_cnt = 1.0f / fmaxf((float)cnt, 1e-9f);
  if (t < 96) {
    float4 a = part[0][t], b = part[1][t], c = part[2][t], d2 = part[3][t];
    m4.x = (a.x + b.x + c.x + d2.x) * inv_cnt;
    m4.y = (a.y + b.y + c.y + d2.y) * inv_cnt;
    m4.z = (a.z + b.z + c.z + d2.z) * inv_cnt;
    m4.w = (a.w + b.w + c.w + d2.w) * inv_cnt;
    dot = m4.x * m4.x + m4.y * m4.y + m4.z * m4.z + m4.w * m4.w;
  }
#pragma unroll
  for (int o = 32; o; o >>= 1) dot += __shfl_down(dot, o);
  __shared__ float wpart[6];
  if ((t & 63) == 0) wpart[t >> 6] = dot;
  __syncthreads();
  float tot = 0.f;
#pragma unroll
  for (int i = 0; i < 6; ++i) tot += wpart[i];
  float inv = 1.0f / fmaxf(sqrtf(tot), 1e-12f);
  if (t < 96) {
    uint2 o;
    o.x = (uint_)f2bf(m4.x * inv) | ((uint_)f2bf(m4.y * inv) << 16);
    o.y = (uint_)f2bf(m4.z * inv) | ((uint_)f2bf(m4.w * inv) << 16);
    ((uint2*)(out + (size_t)n * D))[t] = o;
  }
}

// ---- unified weight prep: 14 slots of [384 n][384 k] bf16 in wbuf ----
// type 1 (fused q) additionally folds p_rel[h] * 0.125 into the rows.
__global__ void prepw_kernel(const float* __restrict__ lin_W, const float* __restrict__ kW,
                             const float* __restrict__ qW, const float* __restrict__ vW,
                             const float* __restrict__ aW, const float* __restrict__ a_rel,
                             const float* __restrict__ m_rel, const float* __restrict__ p_rel,
                             unsigned short* __restrict__ wbuf) {
  int z = blockIdx.z;
  const float* src; const float* rel = nullptr; const float* prl = nullptr; int type = 0;
  switch (z) {
    case 0: src = lin_W; break;
    case 1: src = lin_W + WSZ; break;
    case 2: src = kW; break;
    case 3: type = 1; src = qW; rel = a_rel; prl = p_rel; break;
    case 4: type = 2; src = vW; rel = m_rel + RSZ; break;
    case 5: src = kW + WSZ; break;
    case 6: type = 1; src = qW + WSZ; rel = a_rel + RSZ; prl = p_rel + H; break;
    case 7: type = 2; src = vW + WSZ; rel = m_rel; break;
    case 8: type = 1; src = qW + 2 * WSZ; rel = a_rel + 2 * RSZ; prl = p_rel + 2 * H; break;
    case 9: src = kW + 3 * WSZ; break;
    case 10: type = 2; src = vW + 3 * WSZ; rel = m_rel + 2 * RSZ; break;
    case 11: src = aW; break;
    case 12: src = aW + WSZ; break;
    default: src = aW + 2 * WSZ; break;
  }
  unsigned short* dst = wbuf + (size_t)z * WSZ;
  int tx = threadIdx.x, ty = threadIdx.y;
  int bx = blockIdx.x * 32;  // k range
  int by = blockIdx.y * 32;  // n range
  if (type == 0) {
    __shared__ float tile[32][33];
    tile[ty][tx] = src[(size_t)(bx + ty) * D + by + tx];
    __syncthreads();
    dst[(size_t)(by + ty) * D + bx + tx] = f2bf(tile[tx][ty]);
  } else if (type == 1) {
    int h = by >> 6, d0 = by & 63;
    float sc = prl[h] * 0.125f;
    __shared__ float Wt_[32][65], Rt[32][65];
#pragma unroll
    for (int half = 0; half < 2; ++half) {
      Wt_[ty][tx + half * 32] = src[(size_t)(bx + ty) * D + h * 64 + tx + half * 32];
      Rt[ty][tx + half * 32] = rel[(size_t)h * 4096 + (size_t)(d0 + ty) * 64 + tx + half * 32];
    }
    __syncthreads();
    float s = 0.f;
#pragma unroll 16
    for (int f = 0; f < 64; ++f) s += Wt_[tx][f] * Rt[ty][f];
    dst[(size_t)(by + ty) * D + bx + tx] = f2bf(s * sc);
  } else {
    int h = by >> 6, f0 = by & 63;
    __shared__ float Wt_[32][65];
    __shared__ float Mt[64][33];
#pragma unroll
    for (int half = 0; half < 2; ++half) {
      Wt_[ty][tx + half * 32] = src[(size_t)(bx + ty) * D + h * 64 + tx + half * 32];
      Mt[ty * 2 + half][tx] = rel[(size_t)h * 4096 + (size_t)(ty * 2 + half) * 64 + f0 + tx];
    }
    __syncthreads();
    float s = 0.f;
#pragma unroll 16
    for (int d = 0; d < 64; ++d) s += Wt_[tx][d] * Mt[d][ty];
    dst[(size_t)(by + ty) * D + bx + tx] = f2bf(s);
  }
}

// fused bias vector: [bM1(1152) | bC1(1152) | bM2(384) | bC2(768)]; tq sections p_rel-scaled.
__global__ void prepb_kernel(const float* __restrict__ kb, const float* __restrict__ qb,
                             const float* __restrict__ vb, const float* __restrict__ a_rel,
                             const float* __restrict__ m_rel, const float* __restrict__ p_rel,
                             float* __restrict__ bbuf) {
  int i = blockIdx.x * 256 + threadIdx.x;
  if (i >= 3456) return;
  int gemm, col;
  if (i < 1152) { gemm = 0; col = i; }
  else if (i < 2304) { gemm = 1; col = i - 1152; }
  else if (i < 2688) { gemm = 2; col = i - 2304; }
  else { gemm = 3; col = i - 2688; }
  int sec = col / D, j = col % D, h = j >> 6, r = j & 63;
  float out = 0.f;
  if (gemm == 0) {
    if (sec == 0) out = kb[j];
    else if (sec == 1) {
      const float* R = a_rel + (size_t)h * 4096 + (size_t)r * 64;
      float s = 0.f; for (int f = 0; f < 64; ++f) s += qb[h * 64 + f] * R[f];
      out = s * p_rel[h] * 0.125f;
    } else {
      const float* Mm = m_rel + RSZ + (size_t)h * 4096;
      float s = 0.f; for (int d = 0; d < 64; ++d) s += vb[h * 64 + d] * Mm[d * 64 + r]; out = s;
    }
  } else if (gemm == 1) {
    if (sec == 0) out = kb[D + j];
    else if (sec == 1) {
      const float* R = a_rel + RSZ + (size_t)h * 4096 + (size_t)r * 64;
      float s = 0.f; for (int f = 0; f < 64; ++f) s += qb[D + h * 64 + f] * R[f];
      out = s * p_rel[H + h] * 0.125f;
    } else {
      const float* Mm = m_rel + (size_t)h * 4096;
      float s = 0.f; for (int d = 0; d < 64; ++d) s += vb[D + h * 64 + d] * Mm[d * 64 + r]; out = s;
    }
  } else if (gemm == 2) {
    const float* R = a_rel + 2 * RSZ + (size_t)h * 4096 + (size_t)r * 64;
    float s = 0.f; for (int f = 0; f < 64; ++f) s += qb[2 * D + h * 64 + f] * R[f];
    out = s * p_rel[2 * H + h] * 0.125f;
  } else {
    if (sec == 0) out = kb[3 * D + j];
    else {
      const float* Mm = m_rel + 2 * RSZ + (size_t)h * 4096;
      float s = 0.f; for (int d = 0; d < 64; ++d) s += vb[3 * D + h * 64 + d] * Mm[d * 64 + r]; out = s;
    }
  }
  bbuf[i] = out;
}

// ---------------- CSR build ----------------
__global__ void count2_kernel(const int* __restrict__ d0, const int* __restrict__ d1,
                              int* __restrict__ deg0, int* __restrict__ deg1, int E) {
  int e = blockIdx.x * blockDim.x + threadIdx.x;
  if (e < E) atomicAdd(&deg0[d0[e]], 1);
  else if (e < 2 * E) atomicAdd(&deg1[d1[e - E]], 1);
}

// wave-shuffle scan: 3 barriers per 1024-chunk
__global__ void scan2_kernel(const int* __restrict__ deg0, int* __restrict__ off0, int N0,
                             const int* __restrict__ deg1, int* __restrict__ off1, int N1) {
  const int* deg = blockIdx.x ? deg1 : deg0;
  int* off = blockIdx.x ? off1 : off0;
  int N = blockIdx.x ? N1 : N0;
  __shared__ int wsum[16];
  __shared__ int carrySh;
  int tid = threadIdx.x;
  int lane = tid & 63, wid = tid >> 6;
  if (tid == 0) carrySh = 0;
  __syncthreads();
  for (int base = 0; base < N; base += 1024) {
    int i = base + tid;
    int v = (i < N) ? deg[i] : 0;
    int s = v;
#pragma unroll
    for (int o = 1; o < 64; o <<= 1) {
      int t = __shfl_up(s, o);
      if (lane >= o) s += t;
    }
    if (lane == 63) wsum[wid] = s;
    __syncthreads();
    int wpre = 0;
    for (int j = 0; j < wid; ++j) wpre += wsum[j];
    int c = carrySh;
    if (i < N) off[i] = c + wpre + s - v;
    __syncthreads();
    if (tid == 1023) carrySh = c + wpre + s;
    __syncthreads();
  }
  if (tid == 0) off[N] = carrySh;
}

__global__ void scatter2_kernel(const int* __restrict__ d0, const int* __restrict__ s0,
                                const int* __restrict__ off0, int* __restrict__ cur0,
                                int* __restrict__ el0,
                                const int* __restrict__ d1, const int* __restrict__ s1,
                                const int* __restrict__ off1, int* __restrict__ cur1,
                                int* __restrict__ el1, int E) {
  int e = blockIdx.x * blockDim.x + threadIdx.x;
  if (e < E) {
    int d = d0[e];
    el0[off0[d] + atomicAdd(&cur0[d], 1)] = s0[e];
  } else if (e < 2 * E) {
    int ee = e - E;
    int d = d1[ee];
    el1[off1[d] + atomicAdd(&cur1[d], 1)] = s1[ee];
  }
}

// ---------------- fused per-dst attention, u32-vectorized, 4-edge unrolled ----------------
// tq carries p_rel[h]/8 folded in at prep time. lane l, slot j: u32 l+64j of the 384-bf16 row.
struct AttnP {
  const unsigned short* kb;
  const unsigned short* tqb;
  const unsigned short* vmb;
  const int* off;
  const int* elist;
  unsigned short* aggb;
  int N, sk, st, sv, nb;
};

__global__ void attn_kernel(AttnP a0, AttnP a1) {
  bool first = (int)blockIdx.x < a0.nb;
  AttnP a = first ? a0 : a1;
  int bx = first ? (int)blockIdx.x : (int)blockIdx.x - a0.nb;
  int node = bx * 4 + (threadIdx.x >> 6);
  int lane = threadIdx.x & 63;
  if (node >= a.N) return;
  int e0 = a.off[node], e1 = a.off[node + 1];
  const uint_* tq32 = (const uint_*)(a.tqb + (size_t)node * a.st);
  float tq0[3], tq1[3], m[3], den[3], ac0[3], ac1[3];
#pragma unroll
  for (int j = 0; j < 3; ++j) {
    uint_ u = tq32[lane + 64 * j];
    tq0[j] = blo(u); tq1[j] = bhi(u);
    m[j] = -1e30f; den[j] = 0.f; ac0[j] = 0.f; ac1[j] = 0.f;
  }
  int i = e0;
  for (; i + 4 <= e1; i += 4) {
    int s[4];
#pragma unroll
    for (int u = 0; u < 4; ++u) s[u] = a.elist[i + u];
    uint_ kk[4][3], vv[4][3];
#pragma unroll
    for (int u = 0; u < 4; ++u) {
      const uint_* kp = (const uint_*)(a.kb + (size_t)s[u] * a.sk);
      const uint_* vp = (const uint_*)(a.vmb + (size_t)s[u] * a.sv);
#pragma unroll
      for (int j = 0; j < 3; ++j) { kk[u][j] = kp[lane + 64 * j]; vv[u][j] = vp[lane + 64 * j]; }
    }
    float p[4][3];
#pragma unroll
    for (int u = 0; u < 4; ++u)
#pragma unroll
      for (int j = 0; j < 3; ++j)
        p[u][j] = blo(kk[u][j]) * tq0[j] + bhi(kk[u][j]) * tq1[j];
#pragma unroll
    for (int o = 1; o <= 16; o <<= 1)
#pragma unroll
      for (int u = 0; u < 4; ++u)
#pragma unroll
        for (int j = 0; j < 3; ++j) p[u][j] += __shfl_xor(p[u][j], o);
#pragma unroll
    for (int j = 0; j < 3; ++j) {
      float mx = fmaxf(fmaxf(p[0][j], p[1][j]), fmaxf(p[2][j], p[3][j]));
      float mn = fmaxf(m[j], mx);
      float r = __expf(m[j] - mn);
      float e_[4];
#pragma unroll
      for (int u = 0; u < 4; ++u) e_[u] = __expf(p[u][j] - mn);
      den[j] = den[j] * r + e_[0] + e_[1] + e_[2] + e_[3];
      float a0_ = ac0[j] * r, a1_ = ac1[j] * r;
#pragma unroll
      for (int u = 0; u < 4; ++u) {
        a0_ += e_[u] * blo(vv[u][j]);
        a1_ += e_[u] * bhi(vv[u][j]);
      }
      ac0[j] = a0_; ac1[j] = a1_; m[j] = mn;
    }
  }
  for (; i < e1; ++i) {
    int s0 = a.elist[i];
    const uint_* k0 = (const uint_*)(a.kb + (size_t)s0 * a.sk);
    const uint_* v0 = (const uint_*)(a.vmb + (size_t)s0 * a.sv);
    float pa[3]; uint_ va[3];
#pragma unroll
    for (int j = 0; j < 3; ++j) {
      uint_ ka = k0[lane + 64 * j];
      va[j] = v0[lane + 64 * j];
      pa[j] = blo(ka) * tq0[j] + bhi(ka) * tq1[j];
    }
#pragma unroll
    for (int o = 1; o <= 16; o <<= 1)
#pragma unroll
      for (int j = 0; j < 3; ++j) pa[j] += __shfl_xor(pa[j], o);
#pragma unroll
    for (int j = 0; j < 3; ++j) {
      float mn = fmaxf(m[j], pa[j]);
      float r = __expf(m[j] - mn);
      float p0 = __expf(pa[j] - mn);
      den[j] = den[j] * r + p0;
      ac0[j] = ac0[j] * r + p0 * blo(va[j]);
      ac1[j] = ac1[j] * r + p0 * bhi(va[j]);
      m[j] = mn;
    }
  }
  uint_* op32 = (uint_*)(a.aggb + (size_t)node * D);
#pragma unroll
  for (int j = 0; j < 3; ++j) {
    float o0 = (e1 > e0) ? ac0[j] / den[j] : 0.f;
    float o1 = (e1 > e0) ? ac1[j] / den[j] : 0.f;
    op32[lane + 64 * j] = (uint_)f2bf(geluf(o0)) | ((uint_)f2bf(geluf(o1)) << 16);
  }
}

// ---------------- MFMA bf16 GEMM, dual-problem, double-buffered ----------------
struct GemmP {
  const unsigned short* A;
  const unsigned short* Wt;
  const float* bias;
  float* Cf;
  unsigned short* Cb;
  const float* xold;
  const float* skipPtr;
  int M, N, cpitch, relu;
};

__global__ __launch_bounds__(256) void gemm_bf16(GemmP q0, GemmP q1) {
  GemmP p = blockIdx.z ? q1 : q0;
  const int bm = blockIdx.x * 128, bn = blockIdx.y * 128;
  if (bm >= p.M || bn >= p.N) return;
  __shared__ __align__(16) unsigned short As[2][128 * 64];
  __shared__ __align__(16) unsigned short Bs[2][128 * 64];
  const int tid = threadIdx.x;
  const int w = tid >> 6, lane = tid & 63;

  auto stage = [&](int t, int buf) {
#pragma unroll
    for (int i = 0; i < 4; ++i) {
      int cid = (w * 4 + i) * 64 + lane;
      int row = cid >> 3;
      int cg = (cid & 7) ^ (row & 7);
      int grow = bm + row;
      if (grow >= p.M) grow = p.M - 1;
      const unsigned short* gp = p.A + (size_t)grow * D + t * 64 + cg * 8;
      __builtin_amdgcn_global_load_lds((const __attribute__((address_space(1))) void*)gp,
                                       (__attribute__((address_space(3))) void*)&As[buf][(w * 4 + i) * 512],
                                       16, 0, 0);
    }
#pragma unroll
    for (int i = 0; i < 4; ++i) {
      int cid = (w * 4 + i) * 64 + lane;
      int row = cid >> 3;
      int cg = (cid & 7) ^ (row & 7);
      const unsigned short* gp = p.Wt + (size_t)(bn + row) * D + t * 64 + cg * 8;
      __builtin_amdgcn_global_load_lds((const __attribute__((address_space(1))) void*)gp,
                                       (__attribute__((address_space(3))) void*)&Bs[buf][(w * 4 + i) * 512],
                                       16, 0, 0);
    }
  };

  stage(0, 0);
  __syncthreads();

  const int wr = w >> 1, wc = w & 1;
  const int la = lane & 15, hi = lane >> 4;
  f32x4 acc[4][4] = {};

  for (int t = 0; t < 6; ++t) {
    if (t < 5) stage(t + 1, (t + 1) & 1);
    const unsigned short* Ab = As[t & 1];
    const unsigned short* Bb = Bs[t & 1];
#pragma unroll
    for (int ks = 0; ks < 2; ++ks) {
      int c = ks * 4 + hi;
      short8 af[4], bfr[4];
#pragma unroll
      for (int mi = 0; mi < 4; ++mi) {
        int row = wr * 64 + mi * 16 + la;
        af[mi] = *(const short8*)&Ab[row * 64 + ((c ^ (row & 7)) * 8)];
      }
#pragma unroll
      for (int n = 0; n < 4; ++n) {
        int col = wc * 64 + n * 16 + la;
        bfr[n] = *(const short8*)&Bb[col * 64 + ((c ^ (col & 7)) * 8)];
      }
#pragma unroll
      for (int mi = 0; mi < 4; ++mi)
#pragma unroll
        for (int n = 0; n < 4; ++n)
          acc[mi][n] = __builtin_amdgcn_mfma_f32_16x16x32_bf16(af[mi], bfr[n], acc[mi][n], 0, 0, 0);
    }
    __syncthreads();
  }

  float sa = 0.f;
  if (p.xold) sa = 1.0f / (1.0f + __expf(-*p.skipPtr));
#pragma unroll
  for (int mi = 0; mi < 4; ++mi) {
#pragma unroll
    for (int n = 0; n < 4; ++n) {
#pragma unroll
      for (int r = 0; r < 4; ++r) {
        int row = bm + wr * 64 + mi * 16 + hi * 4 + r;
        int col = bn + wc * 64 + n * 16 + la;
        if (row >= p.M) continue;
        float v = acc[mi][n][r] + p.bias[col];
        if (p.relu) v = fmaxf(v, 0.f);
        if (p.xold) v = sa * v + (1.0f - sa) * p.xold[(size_t)row * D + col];
        if (p.Cf) p.Cf[(size_t)row * p.cpitch + col] = v;
        if (p.Cb) p.Cb[(size_t)row * p.cpitch + col] = f2bf(v);
      }
    }
  }
}

extern "C" void kernel_launch(void* const* d_in, const int* in_sizes, int n_in,
                              void* d_out, int out_size, void* d_ws, size_t ws_size,
                              hipStream_t stream) {
  const float* tok_msg = (const float*)d_in[0];
  const float* tok_con = (const float*)d_in[1];
  const int* ids_msg = (const int*)d_in[2];
  const int* ids_con = (const int*)d_in[3];
  const int* src_cm = (const int*)d_in[4];
  const int* dst_cm = (const int*)d_in[5];
  const int* src_mc = (const int*)d_in[6];
  const int* dst_mc = (const int*)d_in[7];
  const float* lin_W = (const float*)d_in[8];
  const float* lin_b = (const float*)d_in[9];
  const float* kW = (const float*)d_in[10];
  const float* kb = (const float*)d_in[11];
  const float* qW = (const float*)d_in[12];
  const float* qb = (const float*)d_in[13];
  const float* vW = (const float*)d_in[14];
  const float* vb = (const float*)d_in[15];
  const float* aW = (const float*)d_in[16];
  const float* ab = (const float*)d_in[17];
  const float* a_rel = (const float*)d_in[18];
  const float* m_rel = (const float*)d_in[19];
  const float* p_rel = (const float*)d_in[20];
  const float* skip = (const float*)d_in[21];

  const int NM = in_sizes[2] / L;
  const int NC = in_sizes[3] / L;
  const int E = in_sizes[4];

  char* wsb = (char*)d_ws;
  size_t woff = 0;
  auto alloc = [&](size_t bytes) {
    woff = (woff + 255) & ~(size_t)255;
    void* p = wsb + woff;
    woff += bytes;
    return p;
  };
  const size_t NMe = (size_t)NM * D, NCe = (size_t)NC * D;
  unsigned short* poolM = (unsigned short*)alloc(NMe * 2);
  unsigned short* poolC = (unsigned short*)alloc(NCe * 2);
  float* x0f = (float*)alloc(NMe * 4);
  float* x1f = (float*)alloc(NCe * 4);
  float* xn0f = (float*)alloc(NMe * 4);
  unsigned short* x0b = (unsigned short*)alloc(NMe * 2);
  unsigned short* x1b = (unsigned short*)alloc(NCe * 2);
  unsigned short* xn0b = (unsigned short*)alloc(NMe * 2);
  unsigned short* xn1b = (unsigned short*)alloc(NCe * 2);
  unsigned short* projM1 = (unsigned short*)alloc((size_t)NM * 1152 * 2);
  unsigned short* projC1 = (unsigned short*)alloc((size_t)NC * 1152 * 2);
  unsigned short* projM2 = (unsigned short*)alloc((size_t)NM * 384 * 2);
  unsigned short* projC2 = (unsigned short*)alloc((size_t)NC * 768 * 2);
  unsigned short* aggM = (unsigned short*)alloc(NMe * 2);
  unsigned short* aggC = (unsigned short*)alloc(NCe * 2);
  unsigned short* wbuf = (unsigned short*)alloc(14 * WSZ * 2);
  float* bbuf = (float*)alloc(3456 * 4);
  // CSR ints: ONE contiguous block, hand-sliced (no per-array padding)
  long nz = 2L * NM + 2L * NC;  // deg0|cur0|deg1|cur1 prefix zeroed every launch
  int* ibase = (int*)alloc((size_t)(nz + NM + 1 + NC + 1 + 2L * E) * 4);
  int* deg0 = ibase;
  int* cur0 = deg0 + NM;
  int* deg1 = cur0 + NM;
  int* cur1 = deg1 + NC;
  int* off0 = cur1 + NC;
  int* off1 = off0 + NM + 1;
  int* el0 = off1 + NC + 1;
  int* el1 = el0 + E;

  dim3 b256(256);
  const int mbM = (NM + 127) / 128, mbC = (NC + 127) / 128;
  const int mbMax = (mbM > mbC) ? mbM : mbC;

  // weight & bias prep
  prepw_kernel<<<dim3(12, 12, 14), dim3(32, 32), 0, stream>>>(lin_W, kW, qW, vW, aW, a_rel, m_rel, p_rel, wbuf);
  prepb_kernel<<<14, b256, 0, stream>>>(kb, qb, vb, a_rel, m_rel, p_rel, bbuf);

  // CSR build
  zero_int_kernel<<<64, b256, 0, stream>>>(ibase, nz);
  int eg2 = (2 * E + 255) / 256;
  count2_kernel<<<eg2, b256, 0, stream>>>(dst_cm, dst_mc, deg0, deg1, E);
  scan2_kernel<<<2, 1024, 0, stream>>>(deg0, off0, NM, deg1, off1, NC);
  scatter2_kernel<<<eg2, b256, 0, stream>>>(dst_cm, src_cm, off0, cur0, el0,
                                            dst_mc, src_mc, off1, cur1, el1, E);

  // pooling (one launch both node types)
  pool_norm_kernel<<<NM + NC, D, 0, stream>>>(tok_msg, ids_msg, poolM, NM, tok_con, ids_con, poolC);

  // initial linear (relu), both node types in one launch
  {
    GemmP p0 = {poolM, wbuf, lin_b, x0f, x0b, nullptr, nullptr, NM, D, D, 1};
    GemmP p1 = {poolC, wbuf + WSZ, lin_b + D, x1f, x1b, nullptr, nullptr, NC, D, D, 1};
    gemm_bf16<<<dim3(mbMax, 3, 2), b256, 0, stream>>>(p0, p1);
  }
  // layer 1: fused k|tq|vm projections, both node types
  {
    GemmP p0 = {x0b, wbuf + 2 * WSZ, bbuf, nullptr, projM1, nullptr, nullptr, NM, 1152, 1152, 0};
    GemmP p1 = {x1b, wbuf + 5 * WSZ, bbuf + 1152, nullptr, projC1, nullptr, nullptr, NC, 1152, 1152, 0};
    gemm_bf16<<<dim3(mbMax, 9, 2), b256, 0, stream>>>(p0, p1);
  }
  // layer 1 attention, both edge types in one launch
  {
    AttnP a0 = {projC1, projM1 + 384, projC1 + 768, off0, el0, aggM, NM, 1152, 1152, 1152, (NM + 3) / 4};
    AttnP a1 = {projM1, projC1 + 384, projM1 + 768, off1, el1, aggC, NC, 1152, 1152, 1152, (NC + 3) / 4};
    attn_kernel<<<(NM + 3) / 4 + (NC + 3) / 4, b256, 0, stream>>>(a0, a1);
  }
  // layer 1 a-proj + skip blend
  {
    GemmP p0 = {aggM, wbuf + 11 * WSZ, ab, xn0f, xn0b, x0f, skip + 0, NM, D, D, 0};
    GemmP p1 = {aggC, wbuf + 12 * WSZ, ab + D, nullptr, xn1b, x1f, skip + 1, NC, D, D, 0};
    gemm_bf16<<<dim3(mbMax, 3, 2), b256, 0, stream>>>(p0, p1);
  }
  // layer 2 projections (M: tq only, N=384; C: k|vm, N=768)
  {
    GemmP p0 = {xn0b, wbuf + 8 * WSZ, bbuf + 2304, nullptr, projM2, nullptr, nullptr, NM, 384, 384, 0};
    GemmP p1 = {xn1b, wbuf + 9 * WSZ, bbuf + 2688, nullptr, projC2, nullptr, nullptr, NC, 768, 768, 0};
    gemm_bf16<<<dim3(mbMax, 6, 2), b256, 0, stream>>>(p0, p1);
  }
  // layer 2 attention (edge type 0 only)
  {
    AttnP a0 = {projC2, projM2, projC2 + 384, off0, el0, aggM, NM, 768, 384, 768, (NM + 3) / 4};
    AttnP a1 = a0;
    attn_kernel<<<(NM + 3) / 4, b256, 0, stream>>>(a0, a1);
  }
  // layer 2 a-proj -> d_out (f32)
  {
    GemmP p0 = {aggM, wbuf + 13 * WSZ, ab + 2 * D, (float*)d_out, nullptr, xn0f, skip + 2, NM, D, D, 0};
    GemmP p1 = p0;
    gemm_bf16<<<dim3(mbM, 3, 1), b256, 0, stream>>>(p0, p1);
  }
}

// Round 8
// 689.172 us; speedup vs baseline: 1.0013x; 1.0013x over previous
//
#include <hip/hip_runtime.h>
#include <math.h>

#define H 6
#define DH 64
#define D 384
#define L 16
#define WSZ ((size_t)(D) * (D))
#define RSZ ((size_t)(H) * (DH) * (DH))

typedef __attribute__((ext_vector_type(8))) short short8;
typedef __attribute__((ext_vector_type(4))) float f32x4;
typedef unsigned int uint_;

__device__ __forceinline__ float bf2f(unsigned short u) {
  union { unsigned int i; float f; } x; x.i = ((unsigned int)u) << 16; return x.f;
}
__device__ __forceinline__ unsigned short f2bf(float f) {
  unsigned int x = __float_as_uint(f);
  x = x + 0x7fffu + ((x >> 16) & 1u);
  return (unsigned short)(x >> 16);
}
__device__ __forceinline__ float blo(unsigned int u) { return __uint_as_float(u << 16); }
__device__ __forceinline__ float bhi(unsigned int u) { return __uint_as_float(u & 0xffff0000u); }
__device__ __forceinline__ float geluf(float x) {
  return 0.5f * x * (1.0f + erff(x * 0.70710678118654752f));
}

__global__ void zero_int_kernel(int* p, long n) {
  long i = (long)blockIdx.x * blockDim.x + threadIdx.x;
  long stride = (long)gridDim.x * blockDim.x;
  for (; i < n; i += stride) p[i] = 0;
}

// masked mean pool over L tokens then L2 normalize -> bf16. one block per node (M then C).
// float4 loads: thread t handles channel-quad c4=t%96 over rows rg, rg+4, rg+8, rg+12 (rg=t/96).
__global__ void pool_norm_kernel(const float* __restrict__ tokM, const int* __restrict__ idsM,
                                 unsigned short* __restrict__ outM, int NM,
                                 const float* __restrict__ tokC, const int* __restrict__ idsC,
                                 unsigned short* __restrict__ outC) {
  int n = blockIdx.x;
  const float* tok; const int* ids; unsigned short* out;
  if (n < NM) { tok = tokM; ids = idsM; out = outM; }
  else { n -= NM; tok = tokC; ids = idsC; out = outC; }
  int t = threadIdx.x;
  int rg = t / 96, c4 = t % 96;
  const float4* tp = (const float4*)(tok + (size_t)n * L * D);
  const int* ip = ids + (size_t)n * L;
  int cnt = 0;
#pragma unroll
  for (int l = 0; l < L; ++l) cnt += (ip[l] > 0);
  float4 s = {0.f, 0.f, 0.f, 0.f};
#pragma unroll
  for (int li = 0; li < 4; ++li) {
    int l = rg + li * 4;
    if (ip[l] > 0) {
      float4 v = tp[l * 96 + c4];
      s.x += v.x; s.y += v.y; s.z += v.z; s.w += v.w;
    }
  }
  __shared__ float4 part[4][96];
  part[rg][c4] = s;
  __syncthreads();
  float4 m4 = {0.f, 0.f, 0.f, 0.f};
  float dot = 0.f;
  float inv_cnt = 1.0f / fmaxf((float)cnt, 1e-9f);
  if (t < 96) {
    float4 a = part[0][t], b = part[1][t], c = part[2][t], d2 = part[3][t];
    m4.x = (a.x + b.x + c.x + d2.x) * inv_cnt;
    m4.y = (a.y + b.y + c.y + d2.y) * inv_cnt;
    m4.z = (a.z + b.z + c.z + d2.z) * inv_cnt;
    m4.w = (a.w + b.w + c.w + d2.w) * inv_cnt;
    dot = m4.x * m4.x + m4.y * m4.y + m4.z * m4.z + m4.w * m4.w;
  }
#pragma unroll
  for (int o = 32; o; o >>= 1) dot += __shfl_down(dot, o);
  __shared__ float wpart[6];
  if ((t & 63) == 0) wpart[t >> 6] = dot;
  __syncthreads();
  float tot = 0.f;
#pragma unroll
  for (int i = 0; i < 6; ++i) tot += wpart[i];
  float inv = 1.0f / fmaxf(sqrtf(tot), 1e-12f);
  if (t < 96) {
    uint2 o;
    o.x = (uint_)f2bf(m4.x * inv) | ((uint_)f2bf(m4.y * inv) << 16);
    o.y = (uint_)f2bf(m4.z * inv) | ((uint_)f2bf(m4.w * inv) << 16);
    ((uint2*)(out + (size_t)n * D))[t] = o;
  }
}

// ---- unified weight prep: 14 slots of [384 n][384 k] bf16 in wbuf ----
// type 1 (fused q) additionally folds p_rel[h] * 0.125 into the rows.
__global__ void prepw_kernel(const float* __restrict__ lin_W, const float* __restrict__ kW,
                             const float* __restrict__ qW, const float* __restrict__ vW,
                             const float* __restrict__ aW, const float* __restrict__ a_rel,
                             const float* __restrict__ m_rel, const float* __restrict__ p_rel,
                             unsigned short* __restrict__ wbuf) {
  int z = blockIdx.z;
  const float* src; const float* rel = nullptr; const float* prl = nullptr; int type = 0;
  switch (z) {
    case 0: src = lin_W; break;
    case 1: src = lin_W + WSZ; break;
    case 2: src = kW; break;
    case 3: type = 1; src = qW; rel = a_rel; prl = p_rel; break;
    case 4: type = 2; src = vW; rel = m_rel + RSZ; break;
    case 5: src = kW + WSZ; break;
    case 6: type = 1; src = qW + WSZ; rel = a_rel + RSZ; prl = p_rel + H; break;
    case 7: type = 2; src = vW + WSZ; rel = m_rel; break;
    case 8: type = 1; src = qW + 2 * WSZ; rel = a_rel + 2 * RSZ; prl = p_rel + 2 * H; break;
    case 9: src = kW + 3 * WSZ; break;
    case 10: type = 2; src = vW + 3 * WSZ; rel = m_rel + 2 * RSZ; break;
    case 11: src = aW; break;
    case 12: src = aW + WSZ; break;
    default: src = aW + 2 * WSZ; break;
  }
  unsigned short* dst = wbuf + (size_t)z * WSZ;
  int tx = threadIdx.x, ty = threadIdx.y;
  int bx = blockIdx.x * 32;  // k range
  int by = blockIdx.y * 32;  // n range
  if (type == 0) {
    __shared__ float tile[32][33];
    tile[ty][tx] = src[(size_t)(bx + ty) * D + by + tx];
    __syncthreads();
    dst[(size_t)(by + ty) * D + bx + tx] = f2bf(tile[tx][ty]);
  } else if (type == 1) {
    int h = by >> 6, d0 = by & 63;
    float sc = prl[h] * 0.125f;
    __shared__ float Wt_[32][65], Rt[32][65];
#pragma unroll
    for (int half = 0; half < 2; ++half) {
      Wt_[ty][tx + half * 32] = src[(size_t)(bx + ty) * D + h * 64 + tx + half * 32];
      Rt[ty][tx + half * 32] = rel[(size_t)h * 4096 + (size_t)(d0 + ty) * 64 + tx + half * 32];
    }
    __syncthreads();
    float s = 0.f;
#pragma unroll 16
    for (int f = 0; f < 64; ++f) s += Wt_[tx][f] * Rt[ty][f];
    dst[(size_t)(by + ty) * D + bx + tx] = f2bf(s * sc);
  } else {
    int h = by >> 6, f0 = by & 63;
    __shared__ float Wt_[32][65];
    __shared__ float Mt[64][33];
#pragma unroll
    for (int half = 0; half < 2; ++half) {
      Wt_[ty][tx + half * 32] = src[(size_t)(bx + ty) * D + h * 64 + tx + half * 32];
      Mt[ty * 2 + half][tx] = rel[(size_t)h * 4096 + (size_t)(ty * 2 + half) * 64 + f0 + tx];
    }
    __syncthreads();
    float s = 0.f;
#pragma unroll 16
    for (int d = 0; d < 64; ++d) s += Wt_[tx][d] * Mt[d][ty];
    dst[(size_t)(by + ty) * D + bx + tx] = f2bf(s);
  }
}

// fused bias vector: [bM1(1152) | bC1(1152) | bM2(384) | bC2(768)]; tq sections p_rel-scaled.
__global__ void prepb_kernel(const float* __restrict__ kb, const float* __restrict__ qb,
                             const float* __restrict__ vb, const float* __restrict__ a_rel,
                             const float* __restrict__ m_rel, const float* __restrict__ p_rel,
                             float* __restrict__ bbuf) {
  int i = blockIdx.x * 256 + threadIdx.x;
  if (i >= 3456) return;
  int gemm, col;
  if (i < 1152) { gemm = 0; col = i; }
  else if (i < 2304) { gemm = 1; col = i - 1152; }
  else if (i < 2688) { gemm = 2; col = i - 2304; }
  else { gemm = 3; col = i - 2688; }
  int sec = col / D, j = col % D, h = j >> 6, r = j & 63;
  float out = 0.f;
  if (gemm == 0) {
    if (sec == 0) out = kb[j];
    else if (sec == 1) {
      const float* R = a_rel + (size_t)h * 4096 + (size_t)r * 64;
      float s = 0.f; for (int f = 0; f < 64; ++f) s += qb[h * 64 + f] * R[f];
      out = s * p_rel[h] * 0.125f;
    } else {
      const float* Mm = m_rel + RSZ + (size_t)h * 4096;
      float s = 0.f; for (int d = 0; d < 64; ++d) s += vb[h * 64 + d] * Mm[d * 64 + r]; out = s;
    }
  } else if (gemm == 1) {
    if (sec == 0) out = kb[D + j];
    else if (sec == 1) {
      const float* R = a_rel + RSZ + (size_t)h * 4096 + (size_t)r * 64;
      float s = 0.f; for (int f = 0; f < 64; ++f) s += qb[D + h * 64 + f] * R[f];
      out = s * p_rel[H + h] * 0.125f;
    } else {
      const float* Mm = m_rel + (size_t)h * 4096;
      float s = 0.f; for (int d = 0; d < 64; ++d) s += vb[D + h * 64 + d] * Mm[d * 64 + r]; out = s;
    }
  } else if (gemm == 2) {
    const float* R = a_rel + 2 * RSZ + (size_t)h * 4096 + (size_t)r * 64;
    float s = 0.f; for (int f = 0; f < 64; ++f) s += qb[2 * D + h * 64 + f] * R[f];
    out = s * p_rel[2 * H + h] * 0.125f;
  } else {
    if (sec == 0) out = kb[3 * D + j];
    else {
      const float* Mm = m_rel + 2 * RSZ + (size_t)h * 4096;
      float s = 0.f; for (int d = 0; d < 64; ++d) s += vb[3 * D + h * 64 + d] * Mm[d * 64 + r]; out = s;
    }
  }
  bbuf[i] = out;
}

// ---------------- CSR build ----------------
__global__ void count2_kernel(const int* __restrict__ d0, const int* __restrict__ d1,
                              int* __restrict__ deg0, int* __restrict__ deg1, int E) {
  int e = blockIdx.x * blockDim.x + threadIdx.x;
  if (e < E) atomicAdd(&deg0[d0[e]], 1);
  else if (e < 2 * E) atomicAdd(&deg1[d1[e - E]], 1);
}

// wave-shuffle scan: 3 barriers per 1024-chunk
__global__ void scan2_kernel(const int* __restrict__ deg0, int* __restrict__ off0, int N0,
                             const int* __restrict__ deg1, int* __restrict__ off1, int N1) {
  const int* deg = blockIdx.x ? deg1 : deg0;
  int* off = blockIdx.x ? off1 : off0;
  int N = blockIdx.x ? N1 : N0;
  __shared__ int wsum[16];
  __shared__ int carrySh;
  int tid = threadIdx.x;
  int lane = tid & 63, wid = tid >> 6;
  if (tid == 0) carrySh = 0;
  __syncthreads();
  for (int base = 0; base < N; base += 1024) {
    int i = base + tid;
    int v = (i < N) ? deg[i] : 0;
    int s = v;
#pragma unroll
    for (int o = 1; o < 64; o <<= 1) {
      int t = __shfl_up(s, o);
      if (lane >= o) s += t;
    }
    if (lane == 63) wsum[wid] = s;
    __syncthreads();
    int wpre = 0;
    for (int j = 0; j < wid; ++j) wpre += wsum[j];
    int c = carrySh;
    if (i < N) off[i] = c + wpre + s - v;
    __syncthreads();
    if (tid == 1023) carrySh = c + wpre + s;
    __syncthreads();
  }
  if (tid == 0) off[N] = carrySh;
}

__global__ void scatter2_kernel(const int* __restrict__ d0, const int* __restrict__ s0,
                                const int* __restrict__ off0, int* __restrict__ cur0,
                                int* __restrict__ el0,
                                const int* __restrict__ d1, const int* __restrict__ s1,
                                const int* __restrict__ off1, int* __restrict__ cur1,
                                int* __restrict__ el1, int E) {
  int e = blockIdx.x * blockDim.x + threadIdx.x;
  if (e < E) {
    int d = d0[e];
    el0[off0[d] + atomicAdd(&cur0[d], 1)] = s0[e];
  } else if (e < 2 * E) {
    int ee = e - E;
    int d = d1[ee];
    el1[off1[d] + atomicAdd(&cur1[d], 1)] = s1[ee];
  }
}

// ---------------- fused per-dst attention, u32-vectorized, 4-edge unrolled ----------------
// tq carries p_rel[h]/8 folded in at prep time. lane l, slot j: u32 l+64j of the 384-bf16 row.
struct AttnP {
  const unsigned short* kb;
  const unsigned short* tqb;
  const unsigned short* vmb;
  const int* off;
  const int* elist;
  unsigned short* aggb;
  int N, sk, st, sv, nb;
};

__global__ void attn_kernel(AttnP a0, AttnP a1) {
  bool first = (int)blockIdx.x < a0.nb;
  AttnP a = first ? a0 : a1;
  int bx = first ? (int)blockIdx.x : (int)blockIdx.x - a0.nb;
  int node = bx * 4 + (threadIdx.x >> 6);
  int lane = threadIdx.x & 63;
  if (node >= a.N) return;
  int e0 = a.off[node], e1 = a.off[node + 1];
  const uint_* tq32 = (const uint_*)(a.tqb + (size_t)node * a.st);
  float tq0[3], tq1[3], m[3], den[3], ac0[3], ac1[3];
#pragma unroll
  for (int j = 0; j < 3; ++j) {
    uint_ u = tq32[lane + 64 * j];
    tq0[j] = blo(u); tq1[j] = bhi(u);
    m[j] = -1e30f; den[j] = 0.f; ac0[j] = 0.f; ac1[j] = 0.f;
  }
  int i = e0;
  for (; i + 4 <= e1; i += 4) {
    int s[4];
#pragma unroll
    for (int u = 0; u < 4; ++u) s[u] = a.elist[i + u];
    uint_ kk[4][3], vv[4][3];
#pragma unroll
    for (int u = 0; u < 4; ++u) {
      const uint_* kp = (const uint_*)(a.kb + (size_t)s[u] * a.sk);
      const uint_* vp = (const uint_*)(a.vmb + (size_t)s[u] * a.sv);
#pragma unroll
      for (int j = 0; j < 3; ++j) { kk[u][j] = kp[lane + 64 * j]; vv[u][j] = vp[lane + 64 * j]; }
    }
    float p[4][3];
#pragma unroll
    for (int u = 0; u < 4; ++u)
#pragma unroll
      for (int j = 0; j < 3; ++j)
        p[u][j] = blo(kk[u][j]) * tq0[j] + bhi(kk[u][j]) * tq1[j];
#pragma unroll
    for (int o = 1; o <= 16; o <<= 1)
#pragma unroll
      for (int u = 0; u < 4; ++u)
#pragma unroll
        for (int j = 0; j < 3; ++j) p[u][j] += __shfl_xor(p[u][j], o);
#pragma unroll
    for (int j = 0; j < 3; ++j) {
      float mx = fmaxf(fmaxf(p[0][j], p[1][j]), fmaxf(p[2][j], p[3][j]));
      float mn = fmaxf(m[j], mx);
      float r = __expf(m[j] - mn);
      float e_[4];
#pragma unroll
      for (int u = 0; u < 4; ++u) e_[u] = __expf(p[u][j] - mn);
      den[j] = den[j] * r + e_[0] + e_[1] + e_[2] + e_[3];
      float a0_ = ac0[j] * r, a1_ = ac1[j] * r;
#pragma unroll
      for (int u = 0; u < 4; ++u) {
        a0_ += e_[u] * blo(vv[u][j]);
        a1_ += e_[u] * bhi(vv[u][j]);
      }
      ac0[j] = a0_; ac1[j] = a1_; m[j] = mn;
    }
  }
  for (; i < e1; ++i) {
    int s0 = a.elist[i];
    const uint_* k0 = (const uint_*)(a.kb + (size_t)s0 * a.sk);
    const uint_* v0 = (const uint_*)(a.vmb + (size_t)s0 * a.sv);
    float pa[3]; uint_ va[3];
#pragma unroll
    for (int j = 0; j < 3; ++j) {
      uint_ ka = k0[lane + 64 * j];
      va[j] = v0[lane + 64 * j];
      pa[j] = blo(ka) * tq0[j] + bhi(ka) * tq1[j];
    }
#pragma unroll
    for (int o = 1; o <= 16; o <<= 1)
#pragma unroll
      for (int j = 0; j < 3; ++j) pa[j] += __shfl_xor(pa[j], o);
#pragma unroll
    for (int j = 0; j < 3; ++j) {
      float mn = fmaxf(m[j], pa[j]);
      float r = __expf(m[j] - mn);
      float p0 = __expf(pa[j] - mn);
      den[j] = den[j] * r + p0;
      ac0[j] = ac0[j] * r + p0 * blo(va[j]);
      ac1[j] = ac1[j] * r + p0 * bhi(va[j]);
      m[j] = mn;
    }
  }
  uint_* op32 = (uint_*)(a.aggb + (size_t)node * D);
#pragma unroll
  for (int j = 0; j < 3; ++j) {
    float o0 = (e1 > e0) ? ac0[j] / den[j] : 0.f;
    float o1 = (e1 > e0) ? ac1[j] / den[j] : 0.f;
    op32[lane + 64 * j] = (uint_)f2bf(geluf(o0)) | ((uint_)f2bf(geluf(o1)) << 16);
  }
}

// ---------------- MFMA bf16 GEMM, dual-problem, double-buffered ----------------
struct GemmP {
  const unsigned short* A;
  const unsigned short* Wt;
  const float* bias;
  float* Cf;
  unsigned short* Cb;
  const float* xold;
  const float* skipPtr;
  int M, N, cpitch, relu;
};

__global__ __launch_bounds__(256) void gemm_bf16(GemmP q0, GemmP q1) {
  GemmP p = blockIdx.z ? q1 : q0;
  const int bm = blockIdx.x * 128, bn = blockIdx.y * 128;
  if (bm >= p.M || bn >= p.N) return;
  __shared__ __align__(16) unsigned short As[2][128 * 64];
  __shared__ __align__(16) unsigned short Bs[2][128 * 64];
  const int tid = threadIdx.x;
  const int w = tid >> 6, lane = tid & 63;

  auto stage = [&](int t, int buf) {
#pragma unroll
    for (int i = 0; i < 4; ++i) {
      int cid = (w * 4 + i) * 64 + lane;
      int row = cid >> 3;
      int cg = (cid & 7) ^ (row & 7);
      int grow = bm + row;
      if (grow >= p.M) grow = p.M - 1;
      const unsigned short* gp = p.A + (size_t)grow * D + t * 64 + cg * 8;
      __builtin_amdgcn_global_load_lds((const __attribute__((address_space(1))) void*)gp,
                                       (__attribute__((address_space(3))) void*)&As[buf][(w * 4 + i) * 512],
                                       16, 0, 0);
    }
#pragma unroll
    for (int i = 0; i < 4; ++i) {
      int cid = (w * 4 + i) * 64 + lane;
      int row = cid >> 3;
      int cg = (cid & 7) ^ (row & 7);
      const unsigned short* gp = p.Wt + (size_t)(bn + row) * D + t * 64 + cg * 8;
      __builtin_amdgcn_global_load_lds((const __attribute__((address_space(1))) void*)gp,
                                       (__attribute__((address_space(3))) void*)&Bs[buf][(w * 4 + i) * 512],
                                       16, 0, 0);
    }
  };

  stage(0, 0);
  __syncthreads();

  const int wr = w >> 1, wc = w & 1;
  const int la = lane & 15, hi = lane >> 4;
  f32x4 acc[4][4] = {};

  for (int t = 0; t < 6; ++t) {
    if (t < 5) stage(t + 1, (t + 1) & 1);
    const unsigned short* Ab = As[t & 1];
    const unsigned short* Bb = Bs[t & 1];
#pragma unroll
    for (int ks = 0; ks < 2; ++ks) {
      int c = ks * 4 + hi;
      short8 af[4], bfr[4];
#pragma unroll
      for (int mi = 0; mi < 4; ++mi) {
        int row = wr * 64 + mi * 16 + la;
        af[mi] = *(const short8*)&Ab[row * 64 + ((c ^ (row & 7)) * 8)];
      }
#pragma unroll
      for (int n = 0; n < 4; ++n) {
        int col = wc * 64 + n * 16 + la;
        bfr[n] = *(const short8*)&Bb[col * 64 + ((c ^ (col & 7)) * 8)];
      }
#pragma unroll
      for (int mi = 0; mi < 4; ++mi)
#pragma unroll
        for (int n = 0; n < 4; ++n)
          acc[mi][n] = __builtin_amdgcn_mfma_f32_16x16x32_bf16(af[mi], bfr[n], acc[mi][n], 0, 0, 0);
    }
    __syncthreads();
  }

  float sa = 0.f;
  if (p.xold) sa = 1.0f / (1.0f + __expf(-*p.skipPtr));
#pragma unroll
  for (int mi = 0; mi < 4; ++mi) {
#pragma unroll
    for (int n = 0; n < 4; ++n) {
#pragma unroll
      for (int r = 0; r < 4; ++r) {
        int row = bm + wr * 64 + mi * 16 + hi * 4 + r;
        int col = bn + wc * 64 + n * 16 + la;
        if (row >= p.M) continue;
        float v = acc[mi][n][r] + p.bias[col];
        if (p.relu) v = fmaxf(v, 0.f);
        if (p.xold) v = sa * v + (1.0f - sa) * p.xold[(size_t)row * D + col];
        if (p.Cf) p.Cf[(size_t)row * p.cpitch + col] = v;
        if (p.Cb) p.Cb[(size_t)row * p.cpitch + col] = f2bf(v);
      }
    }
  }
}

extern "C" void kernel_launch(void* const* d_in, const int* in_sizes, int n_in,
                              void* d_out, int out_size, void* d_ws, size_t ws_size,
                              hipStream_t stream) {
  const float* tok_msg = (const float*)d_in[0];
  const float* tok_con = (const float*)d_in[1];
  const int* ids_msg = (const int*)d_in[2];
  const int* ids_con = (const int*)d_in[3];
  const int* src_cm = (const int*)d_in[4];
  const int* dst_cm = (const int*)d_in[5];
  const int* src_mc = (const int*)d_in[6];
  const int* dst_mc = (const int*)d_in[7];
  const float* lin_W = (const float*)d_in[8];
  const float* lin_b = (const float*)d_in[9];
  const float* kW = (const float*)d_in[10];
  const float* kb = (const float*)d_in[11];
  const float* qW = (const float*)d_in[12];
  const float* qb = (const float*)d_in[13];
  const float* vW = (const float*)d_in[14];
  const float* vb = (const float*)d_in[15];
  const float* aW = (const float*)d_in[16];
  const float* ab = (const float*)d_in[17];
  const float* a_rel = (const float*)d_in[18];
  const float* m_rel = (const float*)d_in[19];
  const float* p_rel = (const float*)d_in[20];
  const float* skip = (const float*)d_in[21];

  const int NM = in_sizes[2] / L;
  const int NC = in_sizes[3] / L;
  const int E = in_sizes[4];

  char* wsb = (char*)d_ws;
  size_t woff = 0;
  auto alloc = [&](size_t bytes) {
    woff = (woff + 255) & ~(size_t)255;
    void* p = wsb + woff;
    woff += bytes;
    return p;
  };
  const size_t NMe = (size_t)NM * D, NCe = (size_t)NC * D;
  unsigned short* poolM = (unsigned short*)alloc(NMe * 2);
  unsigned short* poolC = (unsigned short*)alloc(NCe * 2);
  float* x0f = (float*)alloc(NMe * 4);
  float* x1f = (float*)alloc(NCe * 4);
  float* xn0f = (float*)alloc(NMe * 4);
  unsigned short* x0b = (unsigned short*)alloc(NMe * 2);
  unsigned short* x1b = (unsigned short*)alloc(NCe * 2);
  unsigned short* xn0b = (unsigned short*)alloc(NMe * 2);
  unsigned short* xn1b = (unsigned short*)alloc(NCe * 2);
  unsigned short* projM1 = (unsigned short*)alloc((size_t)NM * 1152 * 2);
  unsigned short* projC1 = (unsigned short*)alloc((size_t)NC * 1152 * 2);
  unsigned short* projM2 = (unsigned short*)alloc((size_t)NM * 384 * 2);
  unsigned short* projC2 = (unsigned short*)alloc((size_t)NC * 768 * 2);
  unsigned short* aggM = (unsigned short*)alloc(NMe * 2);
  unsigned short* aggC = (unsigned short*)alloc(NCe * 2);
  unsigned short* wbuf = (unsigned short*)alloc(14 * WSZ * 2);
  float* bbuf = (float*)alloc(3456 * 4);
  // CSR ints: ONE contiguous block, hand-sliced (no per-array padding)
  long nz = 2L * NM + 2L * NC;  // deg0|cur0|deg1|cur1 prefix zeroed every launch
  int* ibase = (int*)alloc((size_t)(nz + NM + 1 + NC + 1 + 2L * E) * 4);
  int* deg0 = ibase;
  int* cur0 = deg0 + NM;
  int* deg1 = cur0 + NM;
  int* cur1 = deg1 + NC;
  int* off0 = cur1 + NC;
  int* off1 = off0 + NM + 1;
  int* el0 = off1 + NC + 1;
  int* el1 = el0 + E;

  dim3 b256(256);
  const int mbM = (NM + 127) / 128, mbC = (NC + 127) / 128;
  const int mbMax = (mbM > mbC) ? mbM : mbC;

  // weight & bias prep
  prepw_kernel<<<dim3(12, 12, 14), dim3(32, 32), 0, stream>>>(lin_W, kW, qW, vW, aW, a_rel, m_rel, p_rel, wbuf);
  prepb_kernel<<<14, b256, 0, stream>>>(kb, qb, vb, a_rel, m_rel, p_rel, bbuf);

  // CSR build
  zero_int_kernel<<<64, b256, 0, stream>>>(ibase, nz);
  int eg2 = (2 * E + 255) / 256;
  count2_kernel<<<eg2, b256, 0, stream>>>(dst_cm, dst_mc, deg0, deg1, E);
  scan2_kernel<<<2, 1024, 0, stream>>>(deg0, off0, NM, deg1, off1, NC);
  scatter2_kernel<<<eg2, b256, 0, stream>>>(dst_cm, src_cm, off0, cur0, el0,
                                            dst_mc, src_mc, off1, cur1, el1, E);

  // pooling (one launch both node types)
  pool_norm_kernel<<<NM + NC, D, 0, stream>>>(tok_msg, ids_msg, poolM, NM, tok_con, ids_con, poolC);

  // initial linear (relu), both node types in one launch
  {
    GemmP p0 = {poolM, wbuf, lin_b, x0f, x0b, nullptr, nullptr, NM, D, D, 1};
    GemmP p1 = {poolC, wbuf + WSZ, lin_b + D, x1f, x1b, nullptr, nullptr, NC, D, D, 1};
    gemm_bf16<<<dim3(mbMax, 3, 2), b256, 0, stream>>>(p0, p1);
  }
  // layer 1: fused k|tq|vm projections, both node types
  {
    GemmP p0 = {x0b, wbuf + 2 * WSZ, bbuf, nullptr, projM1, nullptr, nullptr, NM, 1152, 1152, 0};
    GemmP p1 = {x1b, wbuf + 5 * WSZ, bbuf + 1152, nullptr, projC1, nullptr, nullptr, NC, 1152, 1152, 0};
    gemm_bf16<<<dim3(mbMax, 9, 2), b256, 0, stream>>>(p0, p1);
  }
  // layer 1 attention, both edge types in one launch
  {
    AttnP a0 = {projC1, projM1 + 384, projC1 + 768, off0, el0, aggM, NM, 1152, 1152, 1152, (NM + 3) / 4};
    AttnP a1 = {projM1, projC1 + 384, projM1 + 768, off1, el1, aggC, NC, 1152, 1152, 1152, (NC + 3) / 4};
    attn_kernel<<<(NM + 3) / 4 + (NC + 3) / 4, b256, 0, stream>>>(a0, a1);
  }
  // layer 1 a-proj + skip blend
  {
    GemmP p0 = {aggM, wbuf + 11 * WSZ, ab, xn0f, xn0b, x0f, skip + 0, NM, D, D, 0};
    GemmP p1 = {aggC, wbuf + 12 * WSZ, ab + D, nullptr, xn1b, x1f, skip + 1, NC, D, D, 0};
    gemm_bf16<<<dim3(mbMax, 3, 2), b256, 0, stream>>>(p0, p1);
  }
  // layer 2 projections (M: tq only, N=384; C: k|vm, N=768)
  {
    GemmP p0 = {xn0b, wbuf + 8 * WSZ, bbuf + 2304, nullptr, projM2, nullptr, nullptr, NM, 384, 384, 0};
    GemmP p1 = {xn1b, wbuf + 9 * WSZ, bbuf + 2688, nullptr, projC2, nullptr, nullptr, NC, 768, 768, 0};
    gemm_bf16<<<dim3(mbMax, 6, 2), b256, 0, stream>>>(p0, p1);
  }
  // layer 2 attention (edge type 0 only)
  {
    AttnP a0 = {projC2, projM2, projC2 + 384, off0, el0, aggM, NM, 768, 384, 768, (NM + 3) / 4};
    AttnP a1 = a0;
    attn_kernel<<<(NM + 3) / 4, b256, 0, stream>>>(a0, a1);
  }
  // layer 2 a-proj -> d_out (f32)
  {
    GemmP p0 = {aggM, wbuf + 13 * WSZ, ab + 2 * D, (float*)d_out, nullptr, xn0f, skip + 2, NM, D, D, 0};
    GemmP p1 = p0;
    gemm_bf16<<<dim3(mbM, 3, 1), b256, 0, stream>>>(p0, p1);
  }
}

// Round 9
// 686.589 us; speedup vs baseline: 1.0051x; 1.0038x over previous
//
#include <hip/hip_runtime.h>
#include <math.h>

#define H 6
#define DH 64
#define D 384
#define L 16
#define WSZ ((size_t)(D) * (D))
#define RSZ ((size_t)(H) * (DH) * (DH))

typedef __attribute__((ext_vector_type(8))) short short8;
typedef __attribute__((ext_vector_type(4))) float f32x4;
typedef unsigned int uint_;

__device__ __forceinline__ float bf2f(unsigned short u) {
  union { unsigned int i; float f; } x; x.i = ((unsigned int)u) << 16; return x.f;
}
__device__ __forceinline__ unsigned short f2bf(float f) {
  unsigned int x = __float_as_uint(f);
  x = x + 0x7fffu + ((x >> 16) & 1u);
  return (unsigned short)(x >> 16);
}
__device__ __forceinline__ float blo(unsigned int u) { return __uint_as_float(u << 16); }
__device__ __forceinline__ float bhi(unsigned int u) { return __uint_as_float(u & 0xffff0000u); }
__device__ __forceinline__ float geluf(float x) {
  return 0.5f * x * (1.0f + erff(x * 0.70710678118654752f));
}

__global__ void zero_int_kernel(int* p, long n) {
  long i = (long)blockIdx.x * blockDim.x + threadIdx.x;
  long stride = (long)gridDim.x * blockDim.x;
  for (; i < n; i += stride) p[i] = 0;
}

// masked mean pool over L tokens then L2 normalize -> bf16. one block per node (M then C).
// float4 loads: thread t handles channel-quad c4=t%96 over rows rg, rg+4, rg+8, rg+12 (rg=t/96).
__global__ void pool_norm_kernel(const float* __restrict__ tokM, const int* __restrict__ idsM,
                                 unsigned short* __restrict__ outM, int NM,
                                 const float* __restrict__ tokC, const int* __restrict__ idsC,
                                 unsigned short* __restrict__ outC) {
  int n = blockIdx.x;
  const float* tok; const int* ids; unsigned short* out;
  if (n < NM) { tok = tokM; ids = idsM; out = outM; }
  else { n -= NM; tok = tokC; ids = idsC; out = outC; }
  int t = threadIdx.x;
  int rg = t / 96, c4 = t % 96;
  const float4* tp = (const float4*)(tok + (size_t)n * L * D);
  const int* ip = ids + (size_t)n * L;
  int cnt = 0;
#pragma unroll
  for (int l = 0; l < L; ++l) cnt += (ip[l] > 0);
  float4 s = {0.f, 0.f, 0.f, 0.f};
#pragma unroll
  for (int li = 0; li < 4; ++li) {
    int l = rg + li * 4;
    if (ip[l] > 0) {
      float4 v = tp[l * 96 + c4];
      s.x += v.x; s.y += v.y; s.z += v.z; s.w += v.w;
    }
  }
  __shared__ float4 part[4][96];
  part[rg][c4] = s;
  __syncthreads();
  float4 m4 = {0.f, 0.f, 0.f, 0.f};
  float dot = 0.f;
  float inv_cnt = 1.0f / fmaxf((float)cnt, 1e-9f);
  if (t < 96) {
    float4 a = part[0][t], b = part[1][t], c = part[2][t], d2 = part[3][t];
    m4.x = (a.x + b.x + c.x + d2.x) * inv_cnt;
    m4.y = (a.y + b.y + c.y + d2.y) * inv_cnt;
    m4.z = (a.z + b.z + c.z + d2.z) * inv_cnt;
    m4.w = (a.w + b.w + c.w + d2.w) * inv_cnt;
    dot = m4.x * m4.x + m4.y * m4.y + m4.z * m4.z + m4.w * m4.w;
  }
#pragma unroll
  for (int o = 32; o; o >>= 1) dot += __shfl_down(dot, o);
  __shared__ float wpart[6];
  if ((t & 63) == 0) wpart[t >> 6] = dot;
  __syncthreads();
  float tot = 0.f;
#pragma unroll
  for (int i = 0; i < 6; ++i) tot += wpart[i];
  float inv = 1.0f / fmaxf(sqrtf(tot), 1e-12f);
  if (t < 96) {
    uint2 o;
    o.x = (uint_)f2bf(m4.x * inv) | ((uint_)f2bf(m4.y * inv) << 16);
    o.y = (uint_)f2bf(m4.z * inv) | ((uint_)f2bf(m4.w * inv) << 16);
    ((uint2*)(out + (size_t)n * D))[t] = o;
  }
}

// ---- unified weight+bias prep: z in [0,13] = weight slots, z==14 = bias vector ----
// type 1 (fused q) folds p_rel[h] * 0.125 into rows/bias.
__global__ void prepw_kernel(const float* __restrict__ lin_W, const float* __restrict__ kW,
                             const float* __restrict__ qW, const float* __restrict__ vW,
                             const float* __restrict__ aW, const float* __restrict__ a_rel,
                             const float* __restrict__ m_rel, const float* __restrict__ p_rel,
                             const float* __restrict__ kb, const float* __restrict__ qb,
                             const float* __restrict__ vb,
                             unsigned short* __restrict__ wbuf, float* __restrict__ bbuf) {
  int z = blockIdx.z;
  int tx = threadIdx.x, ty = threadIdx.y;
  if (z == 14) {
    // bias prep: flattened tid over 3456 entries
    int i = (blockIdx.y * 12 + blockIdx.x) * 1024 + ty * 32 + tx;
    if (i >= 3456) return;
    int gemm, col;
    if (i < 1152) { gemm = 0; col = i; }
    else if (i < 2304) { gemm = 1; col = i - 1152; }
    else if (i < 2688) { gemm = 2; col = i - 2304; }
    else { gemm = 3; col = i - 2688; }
    int sec = col / D, j = col % D, h = j >> 6, r = j & 63;
    float out = 0.f;
    if (gemm == 0) {
      if (sec == 0) out = kb[j];
      else if (sec == 1) {
        const float* R = a_rel + (size_t)h * 4096 + (size_t)r * 64;
        float s = 0.f; for (int f = 0; f < 64; ++f) s += qb[h * 64 + f] * R[f];
        out = s * p_rel[h] * 0.125f;
      } else {
        const float* Mm = m_rel + RSZ + (size_t)h * 4096;
        float s = 0.f; for (int d = 0; d < 64; ++d) s += vb[h * 64 + d] * Mm[d * 64 + r]; out = s;
      }
    } else if (gemm == 1) {
      if (sec == 0) out = kb[D + j];
      else if (sec == 1) {
        const float* R = a_rel + RSZ + (size_t)h * 4096 + (size_t)r * 64;
        float s = 0.f; for (int f = 0; f < 64; ++f) s += qb[D + h * 64 + f] * R[f];
        out = s * p_rel[H + h] * 0.125f;
      } else {
        const float* Mm = m_rel + (size_t)h * 4096;
        float s = 0.f; for (int d = 0; d < 64; ++d) s += vb[D + h * 64 + d] * Mm[d * 64 + r]; out = s;
      }
    } else if (gemm == 2) {
      const float* R = a_rel + 2 * RSZ + (size_t)h * 4096 + (size_t)r * 64;
      float s = 0.f; for (int f = 0; f < 64; ++f) s += qb[2 * D + h * 64 + f] * R[f];
      out = s * p_rel[2 * H + h] * 0.125f;
    } else {
      if (sec == 0) out = kb[3 * D + j];
      else {
        const float* Mm = m_rel + 2 * RSZ + (size_t)h * 4096;
        float s = 0.f; for (int d = 0; d < 64; ++d) s += vb[3 * D + h * 64 + d] * Mm[d * 64 + r]; out = s;
      }
    }
    bbuf[i] = out;
    return;
  }
  const float* src; const float* rel = nullptr; const float* prl = nullptr; int type = 0;
  switch (z) {
    case 0: src = lin_W; break;
    case 1: src = lin_W + WSZ; break;
    case 2: src = kW; break;
    case 3: type = 1; src = qW; rel = a_rel; prl = p_rel; break;
    case 4: type = 2; src = vW; rel = m_rel + RSZ; break;
    case 5: src = kW + WSZ; break;
    case 6: type = 1; src = qW + WSZ; rel = a_rel + RSZ; prl = p_rel + H; break;
    case 7: type = 2; src = vW + WSZ; rel = m_rel; break;
    case 8: type = 1; src = qW + 2 * WSZ; rel = a_rel + 2 * RSZ; prl = p_rel + 2 * H; break;
    case 9: src = kW + 3 * WSZ; break;
    case 10: type = 2; src = vW + 3 * WSZ; rel = m_rel + 2 * RSZ; break;
    case 11: src = aW; break;
    case 12: src = aW + WSZ; break;
    default: src = aW + 2 * WSZ; break;
  }
  unsigned short* dst = wbuf + (size_t)z * WSZ;
  int bx = blockIdx.x * 32;  // k range
  int by = blockIdx.y * 32;  // n range
  if (type == 0) {
    __shared__ float tile[32][33];
    tile[ty][tx] = src[(size_t)(bx + ty) * D + by + tx];
    __syncthreads();
    dst[(size_t)(by + ty) * D + bx + tx] = f2bf(tile[tx][ty]);
  } else if (type == 1) {
    int h = by >> 6, d0 = by & 63;
    float sc = prl[h] * 0.125f;
    __shared__ float Wt_[32][65], Rt[32][65];
#pragma unroll
    for (int half = 0; half < 2; ++half) {
      Wt_[ty][tx + half * 32] = src[(size_t)(bx + ty) * D + h * 64 + tx + half * 32];
      Rt[ty][tx + half * 32] = rel[(size_t)h * 4096 + (size_t)(d0 + ty) * 64 + tx + half * 32];
    }
    __syncthreads();
    float s = 0.f;
#pragma unroll 16
    for (int f = 0; f < 64; ++f) s += Wt_[tx][f] * Rt[ty][f];
    dst[(size_t)(by + ty) * D + bx + tx] = f2bf(s * sc);
  } else {
    int h = by >> 6, f0 = by & 63;
    __shared__ float Wt_[32][65];
    __shared__ float Mt[64][33];
#pragma unroll
    for (int half = 0; half < 2; ++half) {
      Wt_[ty][tx + half * 32] = src[(size_t)(bx + ty) * D + h * 64 + tx + half * 32];
      Mt[ty * 2 + half][tx] = rel[(size_t)h * 4096 + (size_t)(ty * 2 + half) * 64 + f0 + tx];
    }
    __syncthreads();
    float s = 0.f;
#pragma unroll 16
    for (int d = 0; d < 64; ++d) s += Wt_[tx][d] * Mt[d][ty];
    dst[(size_t)(by + ty) * D + bx + tx] = f2bf(s);
  }
}

// ---------------- CSR build ----------------
__global__ void count2_kernel(const int* __restrict__ d0, const int* __restrict__ d1,
                              int* __restrict__ deg0, int* __restrict__ deg1, int E) {
  int e = blockIdx.x * blockDim.x + threadIdx.x;
  if (e < E) atomicAdd(&deg0[d0[e]], 1);
  else if (e < 2 * E) atomicAdd(&deg1[d1[e - E]], 1);
}

// wave-shuffle scan: 3 barriers per 1024-chunk
__global__ void scan2_kernel(const int* __restrict__ deg0, int* __restrict__ off0, int N0,
                             const int* __restrict__ deg1, int* __restrict__ off1, int N1) {
  const int* deg = blockIdx.x ? deg1 : deg0;
  int* off = blockIdx.x ? off1 : off0;
  int N = blockIdx.x ? N1 : N0;
  __shared__ int wsum[16];
  __shared__ int carrySh;
  int tid = threadIdx.x;
  int lane = tid & 63, wid = tid >> 6;
  if (tid == 0) carrySh = 0;
  __syncthreads();
  for (int base = 0; base < N; base += 1024) {
    int i = base + tid;
    int v = (i < N) ? deg[i] : 0;
    int s = v;
#pragma unroll
    for (int o = 1; o < 64; o <<= 1) {
      int t = __shfl_up(s, o);
      if (lane >= o) s += t;
    }
    if (lane == 63) wsum[wid] = s;
    __syncthreads();
    int wpre = 0;
    for (int j = 0; j < wid; ++j) wpre += wsum[j];
    int c = carrySh;
    if (i < N) off[i] = c + wpre + s - v;
    __syncthreads();
    if (tid == 1023) carrySh = c + wpre + s;
    __syncthreads();
  }
  if (tid == 0) off[N] = carrySh;
}

__global__ void scatter2_kernel(const int* __restrict__ d0, const int* __restrict__ s0,
                                const int* __restrict__ off0, int* __restrict__ cur0,
                                int* __restrict__ el0,
                                const int* __restrict__ d1, const int* __restrict__ s1,
                                const int* __restrict__ off1, int* __restrict__ cur1,
                                int* __restrict__ el1, int E) {
  int e = blockIdx.x * blockDim.x + threadIdx.x;
  if (e < E) {
    int d = d0[e];
    el0[off0[d] + atomicAdd(&cur0[d], 1)] = s0[e];
  } else if (e < 2 * E) {
    int ee = e - E;
    int d = d1[ee];
    el1[off1[d] + atomicAdd(&cur1[d], 1)] = s1[ee];
  }
}

// ---------------- fused per-dst attention, u32-vectorized, 2-edge unrolled ----------------
// tq carries p_rel[h]/8 folded in at prep time. lane l, slot j: u32 l+64j of the 384-bf16 row.
// 2-edge (not 4): keeps VGPRs <=64 -> 32 waves/CU; occupancy beats ILP for this gather loop.
struct AttnP {
  const unsigned short* kb;
  const unsigned short* tqb;
  const unsigned short* vmb;
  const int* off;
  const int* elist;
  unsigned short* aggb;
  int N, sk, st, sv, nb;
};

__global__ void attn_kernel(AttnP a0, AttnP a1) {
  bool first = (int)blockIdx.x < a0.nb;
  AttnP a = first ? a0 : a1;
  int bx = first ? (int)blockIdx.x : (int)blockIdx.x - a0.nb;
  int node = bx * 4 + (threadIdx.x >> 6);
  int lane = threadIdx.x & 63;
  if (node >= a.N) return;
  int e0 = a.off[node], e1 = a.off[node + 1];
  const uint_* tq32 = (const uint_*)(a.tqb + (size_t)node * a.st);
  float tq0[3], tq1[3], m[3], den[3], ac0[3], ac1[3];
#pragma unroll
  for (int j = 0; j < 3; ++j) {
    uint_ u = tq32[lane + 64 * j];
    tq0[j] = blo(u); tq1[j] = bhi(u);
    m[j] = -1e30f; den[j] = 0.f; ac0[j] = 0.f; ac1[j] = 0.f;
  }
  int i = e0;
  for (; i + 2 <= e1; i += 2) {
    int s0 = a.elist[i], s1 = a.elist[i + 1];
    const uint_* k0 = (const uint_*)(a.kb + (size_t)s0 * a.sk);
    const uint_* k1 = (const uint_*)(a.kb + (size_t)s1 * a.sk);
    const uint_* v0 = (const uint_*)(a.vmb + (size_t)s0 * a.sv);
    const uint_* v1 = (const uint_*)(a.vmb + (size_t)s1 * a.sv);
    float pa[3], pb[3]; uint_ va[3], vb[3];
#pragma unroll
    for (int j = 0; j < 3; ++j) {
      uint_ ka = k0[lane + 64 * j], kbu = k1[lane + 64 * j];
      va[j] = v0[lane + 64 * j]; vb[j] = v1[lane + 64 * j];
      pa[j] = blo(ka) * tq0[j] + bhi(ka) * tq1[j];
      pb[j] = blo(kbu) * tq0[j] + bhi(kbu) * tq1[j];
    }
#pragma unroll
    for (int o = 1; o <= 16; o <<= 1)
#pragma unroll
      for (int j = 0; j < 3; ++j) {
        pa[j] += __shfl_xor(pa[j], o);
        pb[j] += __shfl_xor(pb[j], o);
      }
#pragma unroll
    for (int j = 0; j < 3; ++j) {
      float mn = fmaxf(m[j], fmaxf(pa[j], pb[j]));
      float r = __expf(m[j] - mn);
      float p0 = __expf(pa[j] - mn);
      float p1 = __expf(pb[j] - mn);
      den[j] = den[j] * r + p0 + p1;
      ac0[j] = ac0[j] * r + p0 * blo(va[j]) + p1 * blo(vb[j]);
      ac1[j] = ac1[j] * r + p0 * bhi(va[j]) + p1 * bhi(vb[j]);
      m[j] = mn;
    }
  }
  if (i < e1) {
    int s0 = a.elist[i];
    const uint_* k0 = (const uint_*)(a.kb + (size_t)s0 * a.sk);
    const uint_* v0 = (const uint_*)(a.vmb + (size_t)s0 * a.sv);
    float pa[3]; uint_ va[3];
#pragma unroll
    for (int j = 0; j < 3; ++j) {
      uint_ ka = k0[lane + 64 * j];
      va[j] = v0[lane + 64 * j];
      pa[j] = blo(ka) * tq0[j] + bhi(ka) * tq1[j];
    }
#pragma unroll
    for (int o = 1; o <= 16; o <<= 1)
#pragma unroll
      for (int j = 0; j < 3; ++j) pa[j] += __shfl_xor(pa[j], o);
#pragma unroll
    for (int j = 0; j < 3; ++j) {
      float mn = fmaxf(m[j], pa[j]);
      float r = __expf(m[j] - mn);
      float p0 = __expf(pa[j] - mn);
      den[j] = den[j] * r + p0;
      ac0[j] = ac0[j] * r + p0 * blo(va[j]);
      ac1[j] = ac1[j] * r + p0 * bhi(va[j]);
      m[j] = mn;
    }
  }
  uint_* op32 = (uint_*)(a.aggb + (size_t)node * D);
#pragma unroll
  for (int j = 0; j < 3; ++j) {
    float o0 = (e1 > e0) ? ac0[j] / den[j] : 0.f;
    float o1 = (e1 > e0) ? ac1[j] / den[j] : 0.f;
    op32[lane + 64 * j] = (uint_)f2bf(geluf(o0)) | ((uint_)f2bf(geluf(o1)) << 16);
  }
}

// ---------------- MFMA bf16 GEMM, dual-problem, double-buffered ----------------
struct GemmP {
  const unsigned short* A;
  const unsigned short* Wt;
  const float* bias;
  float* Cf;
  unsigned short* Cb;
  const float* xold;
  const float* skipPtr;
  int M, N, cpitch, relu;
};

__global__ __launch_bounds__(256) void gemm_bf16(GemmP q0, GemmP q1) {
  GemmP p = blockIdx.z ? q1 : q0;
  const int bm = blockIdx.x * 128, bn = blockIdx.y * 128;
  if (bm >= p.M || bn >= p.N) return;
  __shared__ __align__(16) unsigned short As[2][128 * 64];
  __shared__ __align__(16) unsigned short Bs[2][128 * 64];
  const int tid = threadIdx.x;
  const int w = tid >> 6, lane = tid & 63;

  auto stage = [&](int t, int buf) {
#pragma unroll
    for (int i = 0; i < 4; ++i) {
      int cid = (w * 4 + i) * 64 + lane;
      int row = cid >> 3;
      int cg = (cid & 7) ^ (row & 7);
      int grow = bm + row;
      if (grow >= p.M) grow = p.M - 1;
      const unsigned short* gp = p.A + (size_t)grow * D + t * 64 + cg * 8;
      __builtin_amdgcn_global_load_lds((const __attribute__((address_space(1))) void*)gp,
                                       (__attribute__((address_space(3))) void*)&As[buf][(w * 4 + i) * 512],
                                       16, 0, 0);
    }
#pragma unroll
    for (int i = 0; i < 4; ++i) {
      int cid = (w * 4 + i) * 64 + lane;
      int row = cid >> 3;
      int cg = (cid & 7) ^ (row & 7);
      const unsigned short* gp = p.Wt + (size_t)(bn + row) * D + t * 64 + cg * 8;
      __builtin_amdgcn_global_load_lds((const __attribute__((address_space(1))) void*)gp,
                                       (__attribute__((address_space(3))) void*)&Bs[buf][(w * 4 + i) * 512],
                                       16, 0, 0);
    }
  };

  stage(0, 0);
  __syncthreads();

  const int wr = w >> 1, wc = w & 1;
  const int la = lane & 15, hi = lane >> 4;
  f32x4 acc[4][4] = {};

  for (int t = 0; t < 6; ++t) {
    if (t < 5) stage(t + 1, (t + 1) & 1);
    const unsigned short* Ab = As[t & 1];
    const unsigned short* Bb = Bs[t & 1];
#pragma unroll
    for (int ks = 0; ks < 2; ++ks) {
      int c = ks * 4 + hi;
      short8 af[4], bfr[4];
#pragma unroll
      for (int mi = 0; mi < 4; ++mi) {
        int row = wr * 64 + mi * 16 + la;
        af[mi] = *(const short8*)&Ab[row * 64 + ((c ^ (row & 7)) * 8)];
      }
#pragma unroll
      for (int n = 0; n < 4; ++n) {
        int col = wc * 64 + n * 16 + la;
        bfr[n] = *(const short8*)&Bb[col * 64 + ((c ^ (col & 7)) * 8)];
      }
#pragma unroll
      for (int mi = 0; mi < 4; ++mi)
#pragma unroll
        for (int n = 0; n < 4; ++n)
          acc[mi][n] = __builtin_amdgcn_mfma_f32_16x16x32_bf16(af[mi], bfr[n], acc[mi][n], 0, 0, 0);
    }
    __syncthreads();
  }

  float sa = 0.f;
  if (p.xold) sa = 1.0f / (1.0f + __expf(-*p.skipPtr));
#pragma unroll
  for (int mi = 0; mi < 4; ++mi) {
#pragma unroll
    for (int n = 0; n < 4; ++n) {
#pragma unroll
      for (int r = 0; r < 4; ++r) {
        int row = bm + wr * 64 + mi * 16 + hi * 4 + r;
        int col = bn + wc * 64 + n * 16 + la;
        if (row >= p.M) continue;
        float v = acc[mi][n][r] + p.bias[col];
        if (p.relu) v = fmaxf(v, 0.f);
        if (p.xold) v = sa * v + (1.0f - sa) * p.xold[(size_t)row * D + col];
        if (p.Cf) p.Cf[(size_t)row * p.cpitch + col] = v;
        if (p.Cb) p.Cb[(size_t)row * p.cpitch + col] = f2bf(v);
      }
    }
  }
}

extern "C" void kernel_launch(void* const* d_in, const int* in_sizes, int n_in,
                              void* d_out, int out_size, void* d_ws, size_t ws_size,
                              hipStream_t stream) {
  const float* tok_msg = (const float*)d_in[0];
  const float* tok_con = (const float*)d_in[1];
  const int* ids_msg = (const int*)d_in[2];
  const int* ids_con = (const int*)d_in[3];
  const int* src_cm = (const int*)d_in[4];
  const int* dst_cm = (const int*)d_in[5];
  const int* src_mc = (const int*)d_in[6];
  const int* dst_mc = (const int*)d_in[7];
  const float* lin_W = (const float*)d_in[8];
  const float* lin_b = (const float*)d_in[9];
  const float* kW = (const float*)d_in[10];
  const float* kb = (const float*)d_in[11];
  const float* qW = (const float*)d_in[12];
  const float* qb = (const float*)d_in[13];
  const float* vW = (const float*)d_in[14];
  const float* vb = (const float*)d_in[15];
  const float* aW = (const float*)d_in[16];
  const float* ab = (const float*)d_in[17];
  const float* a_rel = (const float*)d_in[18];
  const float* m_rel = (const float*)d_in[19];
  const float* p_rel = (const float*)d_in[20];
  const float* skip = (const float*)d_in[21];

  const int NM = in_sizes[2] / L;
  const int NC = in_sizes[3] / L;
  const int E = in_sizes[4];

  char* wsb = (char*)d_ws;
  size_t woff = 0;
  auto alloc = [&](size_t bytes) {
    woff = (woff + 255) & ~(size_t)255;
    void* p = wsb + woff;
    woff += bytes;
    return p;
  };
  const size_t NMe = (size_t)NM * D, NCe = (size_t)NC * D;
  unsigned short* poolM = (unsigned short*)alloc(NMe * 2);
  unsigned short* poolC = (unsigned short*)alloc(NCe * 2);
  float* x0f = (float*)alloc(NMe * 4);
  float* x1f = (float*)alloc(NCe * 4);
  float* xn0f = (float*)alloc(NMe * 4);
  unsigned short* x0b = (unsigned short*)alloc(NMe * 2);
  unsigned short* x1b = (unsigned short*)alloc(NCe * 2);
  unsigned short* xn0b = (unsigned short*)alloc(NMe * 2);
  unsigned short* xn1b = (unsigned short*)alloc(NCe * 2);
  unsigned short* projM1 = (unsigned short*)alloc((size_t)NM * 1152 * 2);
  unsigned short* projC1 = (unsigned short*)alloc((size_t)NC * 1152 * 2);
  unsigned short* projM2 = (unsigned short*)alloc((size_t)NM * 384 * 2);
  unsigned short* projC2 = (unsigned short*)alloc((size_t)NC * 768 * 2);
  unsigned short* aggM = (unsigned short*)alloc(NMe * 2);
  unsigned short* aggC = (unsigned short*)alloc(NCe * 2);
  unsigned short* wbuf = (unsigned short*)alloc(14 * WSZ * 2);
  float* bbuf = (float*)alloc(3456 * 4);
  // CSR ints: ONE contiguous block, hand-sliced (no per-array padding)
  long nz = 2L * NM + 2L * NC;  // deg0|cur0|deg1|cur1 prefix zeroed every launch
  int* ibase = (int*)alloc((size_t)(nz + NM + 1 + NC + 1 + 2L * E) * 4);
  int* deg0 = ibase;
  int* cur0 = deg0 + NM;
  int* deg1 = cur0 + NM;
  int* cur1 = deg1 + NC;
  int* off0 = cur1 + NC;
  int* off1 = off0 + NM + 1;
  int* el0 = off1 + NC + 1;
  int* el1 = el0 + E;

  dim3 b256(256);
  const int mbM = (NM + 127) / 128, mbC = (NC + 127) / 128;
  const int mbMax = (mbM > mbC) ? mbM : mbC;

  // weight & bias prep (bias folded in as z==14)
  prepw_kernel<<<dim3(12, 12, 15), dim3(32, 32), 0, stream>>>(lin_W, kW, qW, vW, aW, a_rel,
                                                              m_rel, p_rel, kb, qb, vb, wbuf, bbuf);

  // CSR build
  zero_int_kernel<<<64, b256, 0, stream>>>(ibase, nz);
  int eg2 = (2 * E + 255) / 256;
  count2_kernel<<<eg2, b256, 0, stream>>>(dst_cm, dst_mc, deg0, deg1, E);
  scan2_kernel<<<2, 1024, 0, stream>>>(deg0, off0, NM, deg1, off1, NC);
  scatter2_kernel<<<eg2, b256, 0, stream>>>(dst_cm, src_cm, off0, cur0, el0,
                                            dst_mc, src_mc, off1, cur1, el1, E);

  // pooling (one launch both node types)
  pool_norm_kernel<<<NM + NC, D, 0, stream>>>(tok_msg, ids_msg, poolM, NM, tok_con, ids_con, poolC);

  // initial linear (relu), both node types in one launch
  {
    GemmP p0 = {poolM, wbuf, lin_b, x0f, x0b, nullptr, nullptr, NM, D, D, 1};
    GemmP p1 = {poolC, wbuf + WSZ, lin_b + D, x1f, x1b, nullptr, nullptr, NC, D, D, 1};
    gemm_bf16<<<dim3(mbMax, 3, 2), b256, 0, stream>>>(p0, p1);
  }
  // layer 1: fused k|tq|vm projections, both node types
  {
    GemmP p0 = {x0b, wbuf + 2 * WSZ, bbuf, nullptr, projM1, nullptr, nullptr, NM, 1152, 1152, 0};
    GemmP p1 = {x1b, wbuf + 5 * WSZ, bbuf + 1152, nullptr, projC1, nullptr, nullptr, NC, 1152, 1152, 0};
    gemm_bf16<<<dim3(mbMax, 9, 2), b256, 0, stream>>>(p0, p1);
  }
  // layer 1 attention, both edge types in one launch
  {
    AttnP a0 = {projC1, projM1 + 384, projC1 + 768, off0, el0, aggM, NM, 1152, 1152, 1152, (NM + 3) / 4};
    AttnP a1 = {projM1, projC1 + 384, projM1 + 768, off1, el1, aggC, NC, 1152, 1152, 1152, (NC + 3) / 4};
    attn_kernel<<<(NM + 3) / 4 + (NC + 3) / 4, b256, 0, stream>>>(a0, a1);
  }
  // layer 1 a-proj + skip blend
  {
    GemmP p0 = {aggM, wbuf + 11 * WSZ, ab, xn0f, xn0b, x0f, skip + 0, NM, D, D, 0};
    GemmP p1 = {aggC, wbuf + 12 * WSZ, ab + D, nullptr, xn1b, x1f, skip + 1, NC, D, D, 0};
    gemm_bf16<<<dim3(mbMax, 3, 2), b256, 0, stream>>>(p0, p1);
  }
  // layer 2 projections (M: tq only, N=384; C: k|vm, N=768)
  {
    GemmP p0 = {xn0b, wbuf + 8 * WSZ, bbuf + 2304, nullptr, projM2, nullptr, nullptr, NM, 384, 384, 0};
    GemmP p1 = {xn1b, wbuf + 9 * WSZ, bbuf + 2688, nullptr, projC2, nullptr, nullptr, NC, 768, 768, 0};
    gemm_bf16<<<dim3(mbMax, 6, 2), b256, 0, stream>>>(p0, p1);
  }
  // layer 2 attention (edge type 0 only)
  {
    AttnP a0 = {projC2, projM2, projC2 + 384, off0, el0, aggM, NM, 768, 384, 768, (NM + 3) / 4};
    AttnP a1 = a0;
    attn_kernel<<<(NM + 3) / 4, b256, 0, stream>>>(a0, a1);
  }
  // layer 2 a-proj -> d_out (f32)
  {
    GemmP p0 = {aggM, wbuf + 13 * WSZ, ab + 2 * D, (float*)d_out, nullptr, xn0f, skip + 2, NM, D, D, 0};
    GemmP p1 = p0;
    gemm_bf16<<<dim3(mbM, 3, 1), b256, 0, stream>>>(p0, p1);
  }
}

// Round 10
// 609.968 us; speedup vs baseline: 1.1313x; 1.1256x over previous
//
#include <hip/hip_runtime.h>
#include <math.h>

#define H 6
#define DH 64
#define D 384
#define L 16
#define WSZ ((size_t)(D) * (D))
#define RSZ ((size_t)(H) * (DH) * (DH))

typedef __attribute__((ext_vector_type(8))) short short8;
typedef __attribute__((ext_vector_type(4))) float f32x4;
typedef unsigned int uint_;

__device__ __forceinline__ float bf2f(unsigned short u) {
  union { unsigned int i; float f; } x; x.i = ((unsigned int)u) << 16; return x.f;
}
__device__ __forceinline__ unsigned short f2bf(float f) {
  unsigned int x = __float_as_uint(f);
  x = x + 0x7fffu + ((x >> 16) & 1u);
  return (unsigned short)(x >> 16);
}
__device__ __forceinline__ float blo(unsigned int u) { return __uint_as_float(u << 16); }
__device__ __forceinline__ float bhi(unsigned int u) { return __uint_as_float(u & 0xffff0000u); }
__device__ __forceinline__ float geluf(float x) {
  return 0.5f * x * (1.0f + erff(x * 0.70710678118654752f));
}

__global__ void zero_int_kernel(int* p, long n) {
  long i = (long)blockIdx.x * blockDim.x + threadIdx.x;
  long stride = (long)gridDim.x * blockDim.x;
  for (; i < n; i += stride) p[i] = 0;
}

// masked mean pool + L2 normalize -> bf16, WITH embedded edge-degree count.
// one block per node (M then C); each block also counts CH edges (atomic, hides under HBM stream).
__global__ void pool_count_kernel(const float* __restrict__ tokM, const int* __restrict__ idsM,
                                  unsigned short* __restrict__ outM, int NM,
                                  const float* __restrict__ tokC, const int* __restrict__ idsC,
                                  unsigned short* __restrict__ outC,
                                  const int* __restrict__ dc0, const int* __restrict__ dc1,
                                  int* __restrict__ deg0, int* __restrict__ deg1, int E, int CH) {
  // --- embedded degree count ---
  {
    int base = blockIdx.x * CH;
    int e = base + threadIdx.x;
    if (threadIdx.x < CH && e < 2 * E) {
      if (e < E) atomicAdd(&deg0[dc0[e]], 1);
      else atomicAdd(&deg1[dc1[e - E]], 1);
    }
  }
  // --- pooling ---
  int n = blockIdx.x;
  const float* tok; const int* ids; unsigned short* out;
  if (n < NM) { tok = tokM; ids = idsM; out = outM; }
  else { n -= NM; tok = tokC; ids = idsC; out = outC; }
  int t = threadIdx.x;
  int rg = t / 96, c4 = t % 96;
  const float4* tp = (const float4*)(tok + (size_t)n * L * D);
  const int* ip = ids + (size_t)n * L;
  int cnt = 0;
#pragma unroll
  for (int l = 0; l < L; ++l) cnt += (ip[l] > 0);
  float4 s = {0.f, 0.f, 0.f, 0.f};
#pragma unroll
  for (int li = 0; li < 4; ++li) {
    int l = rg + li * 4;
    if (ip[l] > 0) {
      float4 v = tp[l * 96 + c4];
      s.x += v.x; s.y += v.y; s.z += v.z; s.w += v.w;
    }
  }
  __shared__ float4 part[4][96];
  part[rg][c4] = s;
  __syncthreads();
  float4 m4 = {0.f, 0.f, 0.f, 0.f};
  float dot = 0.f;
  float inv_cnt = 1.0f / fmaxf((float)cnt, 1e-9f);
  if (t < 96) {
    float4 a = part[0][t], b = part[1][t], c = part[2][t], d2 = part[3][t];
    m4.x = (a.x + b.x + c.x + d2.x) * inv_cnt;
    m4.y = (a.y + b.y + c.y + d2.y) * inv_cnt;
    m4.z = (a.z + b.z + c.z + d2.z) * inv_cnt;
    m4.w = (a.w + b.w + c.w + d2.w) * inv_cnt;
    dot = m4.x * m4.x + m4.y * m4.y + m4.z * m4.z + m4.w * m4.w;
  }
#pragma unroll
  for (int o = 32; o; o >>= 1) dot += __shfl_down(dot, o);
  __shared__ float wpart[6];
  if ((t & 63) == 0) wpart[t >> 6] = dot;
  __syncthreads();
  float tot = 0.f;
#pragma unroll
  for (int i = 0; i < 6; ++i) tot += wpart[i];
  float inv = 1.0f / fmaxf(sqrtf(tot), 1e-12f);
  if (t < 96) {
    uint2 o;
    o.x = (uint_)f2bf(m4.x * inv) | ((uint_)f2bf(m4.y * inv) << 16);
    o.y = (uint_)f2bf(m4.z * inv) | ((uint_)f2bf(m4.w * inv) << 16);
    ((uint2*)(out + (size_t)n * D))[t] = o;
  }
}

// ---- fused scan (blocks 0,1) + weight/bias prep (blocks 2..2161), 1024 threads ----
// prep: z in [0,13] weight slots ([384 n][384 k] bf16), z==14 bias vector.
// type 1 (fused q) folds p_rel[h] * 0.125 into rows/bias.
__global__ void prepscan_kernel(const float* __restrict__ lin_W, const float* __restrict__ kW,
                                const float* __restrict__ qW, const float* __restrict__ vW,
                                const float* __restrict__ aW, const float* __restrict__ a_rel,
                                const float* __restrict__ m_rel, const float* __restrict__ p_rel,
                                const float* __restrict__ kb, const float* __restrict__ qb,
                                const float* __restrict__ vb,
                                unsigned short* __restrict__ wbuf, float* __restrict__ bbuf,
                                const int* __restrict__ deg0, int* __restrict__ off0, int N0,
                                const int* __restrict__ deg1, int* __restrict__ off1, int N1) {
  int bxg = blockIdx.x;
  int tid = threadIdx.x;
  if (bxg < 2) {
    // ---- wave-shuffle scan ----
    const int* deg = bxg ? deg1 : deg0;
    int* off = bxg ? off1 : off0;
    int N = bxg ? N1 : N0;
    __shared__ int wsum[16];
    __shared__ int carrySh;
    int lane = tid & 63, wid = tid >> 6;
    if (tid == 0) carrySh = 0;
    __syncthreads();
    for (int base = 0; base < N; base += 1024) {
      int i = base + tid;
      int v = (i < N) ? deg[i] : 0;
      int s = v;
#pragma unroll
      for (int o = 1; o < 64; o <<= 1) {
        int t2 = __shfl_up(s, o);
        if (lane >= o) s += t2;
      }
      if (lane == 63) wsum[wid] = s;
      __syncthreads();
      int wpre = 0;
      for (int j = 0; j < wid; ++j) wpre += wsum[j];
      int c = carrySh;
      if (i < N) off[i] = c + wpre + s - v;
      __syncthreads();
      if (tid == 1023) carrySh = c + wpre + s;
      __syncthreads();
    }
    if (tid == 0) off[N] = carrySh;
    return;
  }
  int q = bxg - 2;
  int z = q / 144;
  int r = q % 144;
  int px = r % 12, py = r / 12;
  int tx = tid & 31, ty = tid >> 5;
  if (z == 14) {
    int i = (py * 12 + px) * 1024 + tid;
    if (i >= 3456) return;
    int gemm, col;
    if (i < 1152) { gemm = 0; col = i; }
    else if (i < 2304) { gemm = 1; col = i - 1152; }
    else if (i < 2688) { gemm = 2; col = i - 2304; }
    else { gemm = 3; col = i - 2688; }
    int sec = col / D, j = col % D, h = j >> 6, rr = j & 63;
    float out = 0.f;
    if (gemm == 0) {
      if (sec == 0) out = kb[j];
      else if (sec == 1) {
        const float* R = a_rel + (size_t)h * 4096 + (size_t)rr * 64;
        float s = 0.f; for (int f = 0; f < 64; ++f) s += qb[h * 64 + f] * R[f];
        out = s * p_rel[h] * 0.125f;
      } else {
        const float* Mm = m_rel + RSZ + (size_t)h * 4096;
        float s = 0.f; for (int d = 0; d < 64; ++d) s += vb[h * 64 + d] * Mm[d * 64 + rr]; out = s;
      }
    } else if (gemm == 1) {
      if (sec == 0) out = kb[D + j];
      else if (sec == 1) {
        const float* R = a_rel + RSZ + (size_t)h * 4096 + (size_t)rr * 64;
        float s = 0.f; for (int f = 0; f < 64; ++f) s += qb[D + h * 64 + f] * R[f];
        out = s * p_rel[H + h] * 0.125f;
      } else {
        const float* Mm = m_rel + (size_t)h * 4096;
        float s = 0.f; for (int d = 0; d < 64; ++d) s += vb[D + h * 64 + d] * Mm[d * 64 + rr]; out = s;
      }
    } else if (gemm == 2) {
      const float* R = a_rel + 2 * RSZ + (size_t)h * 4096 + (size_t)rr * 64;
      float s = 0.f; for (int f = 0; f < 64; ++f) s += qb[2 * D + h * 64 + f] * R[f];
      out = s * p_rel[2 * H + h] * 0.125f;
    } else {
      if (sec == 0) out = kb[3 * D + j];
      else {
        const float* Mm = m_rel + 2 * RSZ + (size_t)h * 4096;
        float s = 0.f; for (int d = 0; d < 64; ++d) s += vb[3 * D + h * 64 + d] * Mm[d * 64 + rr]; out = s;
      }
    }
    bbuf[i] = out;
    return;
  }
  const float* src; const float* rel = nullptr; const float* prl = nullptr; int type = 0;
  switch (z) {
    case 0: src = lin_W; break;
    case 1: src = lin_W + WSZ; break;
    case 2: src = kW; break;
    case 3: type = 1; src = qW; rel = a_rel; prl = p_rel; break;
    case 4: type = 2; src = vW; rel = m_rel + RSZ; break;
    case 5: src = kW + WSZ; break;
    case 6: type = 1; src = qW + WSZ; rel = a_rel + RSZ; prl = p_rel + H; break;
    case 7: type = 2; src = vW + WSZ; rel = m_rel; break;
    case 8: type = 1; src = qW + 2 * WSZ; rel = a_rel + 2 * RSZ; prl = p_rel + 2 * H; break;
    case 9: src = kW + 3 * WSZ; break;
    case 10: type = 2; src = vW + 3 * WSZ; rel = m_rel + 2 * RSZ; break;
    case 11: src = aW; break;
    case 12: src = aW + WSZ; break;
    default: src = aW + 2 * WSZ; break;
  }
  unsigned short* dst = wbuf + (size_t)z * WSZ;
  int bx = px * 32;  // k range
  int by = py * 32;  // n range
  if (type == 0) {
    __shared__ float tile[32][33];
    tile[ty][tx] = src[(size_t)(bx + ty) * D + by + tx];
    __syncthreads();
    dst[(size_t)(by + ty) * D + bx + tx] = f2bf(tile[tx][ty]);
  } else if (type == 1) {
    int h = by >> 6, d0 = by & 63;
    float sc = prl[h] * 0.125f;
    __shared__ float Wt_[32][65], Rt[32][65];
#pragma unroll
    for (int half = 0; half < 2; ++half) {
      Wt_[ty][tx + half * 32] = src[(size_t)(bx + ty) * D + h * 64 + tx + half * 32];
      Rt[ty][tx + half * 32] = rel[(size_t)h * 4096 + (size_t)(d0 + ty) * 64 + tx + half * 32];
    }
    __syncthreads();
    float s = 0.f;
#pragma unroll 16
    for (int f = 0; f < 64; ++f) s += Wt_[tx][f] * Rt[ty][f];
    dst[(size_t)(by + ty) * D + bx + tx] = f2bf(s * sc);
  } else {
    int h = by >> 6, f0 = by & 63;
    __shared__ float Wt2[32][65];
    __shared__ float Mt[64][33];
#pragma unroll
    for (int half = 0; half < 2; ++half) {
      Wt2[ty][tx + half * 32] = src[(size_t)(bx + ty) * D + h * 64 + tx + half * 32];
      Mt[ty * 2 + half][tx] = rel[(size_t)h * 4096 + (size_t)(ty * 2 + half) * 64 + f0 + tx];
    }
    __syncthreads();
    float s = 0.f;
#pragma unroll 16
    for (int d = 0; d < 64; ++d) s += Wt2[tx][d] * Mt[d][ty];
    dst[(size_t)(by + ty) * D + bx + tx] = f2bf(s);
  }
}

// ---------------- fused per-dst attention, u32-vectorized, 2-edge unrolled ----------------
struct AttnP {
  const unsigned short* kb;
  const unsigned short* tqb;
  const unsigned short* vmb;
  const int* off;
  const int* elist;
  unsigned short* aggb;
  int N, sk, st, sv, nb;
};

__global__ void attn_kernel(AttnP a0, AttnP a1) {
  bool first = (int)blockIdx.x < a0.nb;
  AttnP a = first ? a0 : a1;
  int bx = first ? (int)blockIdx.x : (int)blockIdx.x - a0.nb;
  int node = bx * 4 + (threadIdx.x >> 6);
  int lane = threadIdx.x & 63;
  if (node >= a.N) return;
  int e0 = a.off[node], e1 = a.off[node + 1];
  const uint_* tq32 = (const uint_*)(a.tqb + (size_t)node * a.st);
  float tq0[3], tq1[3], m[3], den[3], ac0[3], ac1[3];
#pragma unroll
  for (int j = 0; j < 3; ++j) {
    uint_ u = tq32[lane + 64 * j];
    tq0[j] = blo(u); tq1[j] = bhi(u);
    m[j] = -1e30f; den[j] = 0.f; ac0[j] = 0.f; ac1[j] = 0.f;
  }
  int i = e0;
  for (; i + 2 <= e1; i += 2) {
    int s0 = a.elist[i], s1 = a.elist[i + 1];
    const uint_* k0 = (const uint_*)(a.kb + (size_t)s0 * a.sk);
    const uint_* k1 = (const uint_*)(a.kb + (size_t)s1 * a.sk);
    const uint_* v0 = (const uint_*)(a.vmb + (size_t)s0 * a.sv);
    const uint_* v1 = (const uint_*)(a.vmb + (size_t)s1 * a.sv);
    float pa[3], pb[3]; uint_ va[3], vb[3];
#pragma unroll
    for (int j = 0; j < 3; ++j) {
      uint_ ka = k0[lane + 64 * j], kbu = k1[lane + 64 * j];
      va[j] = v0[lane + 64 * j]; vb[j] = v1[lane + 64 * j];
      pa[j] = blo(ka) * tq0[j] + bhi(ka) * tq1[j];
      pb[j] = blo(kbu) * tq0[j] + bhi(kbu) * tq1[j];
    }
#pragma unroll
    for (int o = 1; o <= 16; o <<= 1)
#pragma unroll
      for (int j = 0; j < 3; ++j) {
        pa[j] += __shfl_xor(pa[j], o);
        pb[j] += __shfl_xor(pb[j], o);
      }
#pragma unroll
    for (int j = 0; j < 3; ++j) {
      float mn = fmaxf(m[j], fmaxf(pa[j], pb[j]));
      float r = __expf(m[j] - mn);
      float p0 = __expf(pa[j] - mn);
      float p1 = __expf(pb[j] - mn);
      den[j] = den[j] * r + p0 + p1;
      ac0[j] = ac0[j] * r + p0 * blo(va[j]) + p1 * blo(vb[j]);
      ac1[j] = ac1[j] * r + p0 * bhi(va[j]) + p1 * bhi(vb[j]);
      m[j] = mn;
    }
  }
  if (i < e1) {
    int s0 = a.elist[i];
    const uint_* k0 = (const uint_*)(a.kb + (size_t)s0 * a.sk);
    const uint_* v0 = (const uint_*)(a.vmb + (size_t)s0 * a.sv);
    float pa[3]; uint_ va[3];
#pragma unroll
    for (int j = 0; j < 3; ++j) {
      uint_ ka = k0[lane + 64 * j];
      va[j] = v0[lane + 64 * j];
      pa[j] = blo(ka) * tq0[j] + bhi(ka) * tq1[j];
    }
#pragma unroll
    for (int o = 1; o <= 16; o <<= 1)
#pragma unroll
      for (int j = 0; j < 3; ++j) pa[j] += __shfl_xor(pa[j], o);
#pragma unroll
    for (int j = 0; j < 3; ++j) {
      float mn = fmaxf(m[j], pa[j]);
      float r = __expf(m[j] - mn);
      float p0 = __expf(pa[j] - mn);
      den[j] = den[j] * r + p0;
      ac0[j] = ac0[j] * r + p0 * blo(va[j]);
      ac1[j] = ac1[j] * r + p0 * bhi(va[j]);
      m[j] = mn;
    }
  }
  uint_* op32 = (uint_*)(a.aggb + (size_t)node * D);
#pragma unroll
  for (int j = 0; j < 3; ++j) {
    float o0 = (e1 > e0) ? ac0[j] / den[j] : 0.f;
    float o1 = (e1 > e0) ? ac1[j] / den[j] : 0.f;
    op32[lane + 64 * j] = (uint_)f2bf(geluf(o0)) | ((uint_)f2bf(geluf(o1)) << 16);
  }
}

// ---------------- MFMA bf16 GEMM, dual-problem, double-buffered; z==2 slice = scatter ----------------
struct GemmP {
  const unsigned short* A;
  const unsigned short* Wt;
  const float* bias;
  float* Cf;
  unsigned short* Cb;
  const unsigned short* xold;  // bf16 skip input
  const float* skipPtr;
  int M, N, cpitch, relu;
};
struct ScatP {
  const int *d0, *s0, *off0;
  int *cur0, *el0;
  const int *d1, *s1, *off1;
  int *cur1, *el1;
  int E;
};

__global__ __launch_bounds__(256) void gemm_bf16(GemmP q0, GemmP q1, ScatP sc) {
  if (blockIdx.z == 2) {
    // embedded CSR scatter, grid-strided over both edge types
    int nb = gridDim.x * gridDim.y;
    int flat = blockIdx.y * gridDim.x + blockIdx.x;
    for (int e = flat * 256 + threadIdx.x; e < 2 * sc.E; e += nb * 256) {
      if (e < sc.E) {
        int d = sc.d0[e];
        sc.el0[sc.off0[d] + atomicAdd(&sc.cur0[d], 1)] = sc.s0[e];
      } else {
        int ee = e - sc.E;
        int d = sc.d1[ee];
        sc.el1[sc.off1[d] + atomicAdd(&sc.cur1[d], 1)] = sc.s1[ee];
      }
    }
    return;
  }
  GemmP p = blockIdx.z ? q1 : q0;
  const int bm = blockIdx.x * 128, bn = blockIdx.y * 128;
  if (bm >= p.M || bn >= p.N) return;
  __shared__ __align__(16) unsigned short As[2][128 * 64];
  __shared__ __align__(16) unsigned short Bs[2][128 * 64];
  const int tid = threadIdx.x;
  const int w = tid >> 6, lane = tid & 63;

  auto stage = [&](int t, int buf) {
#pragma unroll
    for (int i = 0; i < 4; ++i) {
      int cid = (w * 4 + i) * 64 + lane;
      int row = cid >> 3;
      int cg = (cid & 7) ^ (row & 7);
      int grow = bm + row;
      if (grow >= p.M) grow = p.M - 1;
      const unsigned short* gp = p.A + (size_t)grow * D + t * 64 + cg * 8;
      __builtin_amdgcn_global_load_lds((const __attribute__((address_space(1))) void*)gp,
                                       (__attribute__((address_space(3))) void*)&As[buf][(w * 4 + i) * 512],
                                       16, 0, 0);
    }
#pragma unroll
    for (int i = 0; i < 4; ++i) {
      int cid = (w * 4 + i) * 64 + lane;
      int row = cid >> 3;
      int cg = (cid & 7) ^ (row & 7);
      const unsigned short* gp = p.Wt + (size_t)(bn + row) * D + t * 64 + cg * 8;
      __builtin_amdgcn_global_load_lds((const __attribute__((address_space(1))) void*)gp,
                                       (__attribute__((address_space(3))) void*)&Bs[buf][(w * 4 + i) * 512],
                                       16, 0, 0);
    }
  };

  stage(0, 0);
  __syncthreads();

  const int wr = w >> 1, wc = w & 1;
  const int la = lane & 15, hi = lane >> 4;
  f32x4 acc[4][4] = {};

  for (int t = 0; t < 6; ++t) {
    if (t < 5) stage(t + 1, (t + 1) & 1);
    const unsigned short* Ab = As[t & 1];
    const unsigned short* Bb = Bs[t & 1];
#pragma unroll
    for (int ks = 0; ks < 2; ++ks) {
      int c = ks * 4 + hi;
      short8 af[4], bfr[4];
#pragma unroll
      for (int mi = 0; mi < 4; ++mi) {
        int row = wr * 64 + mi * 16 + la;
        af[mi] = *(const short8*)&Ab[row * 64 + ((c ^ (row & 7)) * 8)];
      }
#pragma unroll
      for (int n = 0; n < 4; ++n) {
        int col = wc * 64 + n * 16 + la;
        bfr[n] = *(const short8*)&Bb[col * 64 + ((c ^ (col & 7)) * 8)];
      }
#pragma unroll
      for (int mi = 0; mi < 4; ++mi)
#pragma unroll
        for (int n = 0; n < 4; ++n)
          acc[mi][n] = __builtin_amdgcn_mfma_f32_16x16x32_bf16(af[mi], bfr[n], acc[mi][n], 0, 0, 0);
    }
    __syncthreads();
  }

  float sa = 0.f;
  if (p.xold) sa = 1.0f / (1.0f + __expf(-*p.skipPtr));
#pragma unroll
  for (int mi = 0; mi < 4; ++mi) {
#pragma unroll
    for (int n = 0; n < 4; ++n) {
#pragma unroll
      for (int r = 0; r < 4; ++r) {
        int row = bm + wr * 64 + mi * 16 + hi * 4 + r;
        int col = bn + wc * 64 + n * 16 + la;
        if (row >= p.M) continue;
        float v = acc[mi][n][r] + p.bias[col];
        if (p.relu) v = fmaxf(v, 0.f);
        if (p.xold) v = sa * v + (1.0f - sa) * bf2f(p.xold[(size_t)row * D + col]);
        if (p.Cf) p.Cf[(size_t)row * p.cpitch + col] = v;
        if (p.Cb) p.Cb[(size_t)row * p.cpitch + col] = f2bf(v);
      }
    }
  }
}

extern "C" void kernel_launch(void* const* d_in, const int* in_sizes, int n_in,
                              void* d_out, int out_size, void* d_ws, size_t ws_size,
                              hipStream_t stream) {
  const float* tok_msg = (const float*)d_in[0];
  const float* tok_con = (const float*)d_in[1];
  const int* ids_msg = (const int*)d_in[2];
  const int* ids_con = (const int*)d_in[3];
  const int* src_cm = (const int*)d_in[4];
  const int* dst_cm = (const int*)d_in[5];
  const int* src_mc = (const int*)d_in[6];
  const int* dst_mc = (const int*)d_in[7];
  const float* lin_W = (const float*)d_in[8];
  const float* lin_b = (const float*)d_in[9];
  const float* kW = (const float*)d_in[10];
  const float* kb = (const float*)d_in[11];
  const float* qW = (const float*)d_in[12];
  const float* qb = (const float*)d_in[13];
  const float* vW = (const float*)d_in[14];
  const float* vb = (const float*)d_in[15];
  const float* aW = (const float*)d_in[16];
  const float* ab = (const float*)d_in[17];
  const float* a_rel = (const float*)d_in[18];
  const float* m_rel = (const float*)d_in[19];
  const float* p_rel = (const float*)d_in[20];
  const float* skip = (const float*)d_in[21];

  const int NM = in_sizes[2] / L;
  const int NC = in_sizes[3] / L;
  const int E = in_sizes[4];

  char* wsb = (char*)d_ws;
  size_t woff = 0;
  auto alloc = [&](size_t bytes) {
    woff = (woff + 255) & ~(size_t)255;
    void* p = wsb + woff;
    woff += bytes;
    return p;
  };
  const size_t NMe = (size_t)NM * D, NCe = (size_t)NC * D;
  unsigned short* poolM = (unsigned short*)alloc(NMe * 2);
  unsigned short* poolC = (unsigned short*)alloc(NCe * 2);
  unsigned short* x0b = (unsigned short*)alloc(NMe * 2);
  unsigned short* x1b = (unsigned short*)alloc(NCe * 2);
  unsigned short* xn0b = (unsigned short*)alloc(NMe * 2);
  unsigned short* xn1b = (unsigned short*)alloc(NCe * 2);
  unsigned short* projM1 = (unsigned short*)alloc((size_t)NM * 1152 * 2);
  unsigned short* projC1 = (unsigned short*)alloc((size_t)NC * 1152 * 2);
  unsigned short* projM2 = (unsigned short*)alloc((size_t)NM * 384 * 2);
  unsigned short* projC2 = (unsigned short*)alloc((size_t)NC * 768 * 2);
  unsigned short* aggM = (unsigned short*)alloc(NMe * 2);
  unsigned short* aggC = (unsigned short*)alloc(NCe * 2);
  unsigned short* wbuf = (unsigned short*)alloc(14 * WSZ * 2);
  float* bbuf = (float*)alloc(3456 * 4);
  // CSR ints: ONE contiguous block, hand-sliced (no per-array padding)
  long nz = 2L * NM + 2L * NC;  // deg0|cur0|deg1|cur1 prefix zeroed every launch
  int* ibase = (int*)alloc((size_t)(nz + NM + 1 + NC + 1 + 2L * E) * 4);
  int* deg0 = ibase;
  int* cur0 = deg0 + NM;
  int* deg1 = cur0 + NM;
  int* cur1 = deg1 + NC;
  int* off0 = cur1 + NC;
  int* off1 = off0 + NM + 1;
  int* el0 = off1 + NC + 1;
  int* el1 = el0 + E;

  dim3 b256(256);
  const int mbM = (NM + 127) / 128, mbC = (NC + 127) / 128;
  const int mbMax = (mbM > mbC) ? mbM : mbC;
  ScatP scNone = {};
  ScatP scAll = {dst_cm, src_cm, off0, cur0, el0, dst_mc, src_mc, off1, cur1, el1, E};

  // 1) zero deg/cur
  zero_int_kernel<<<64, b256, 0, stream>>>(ibase, nz);

  // 2) pooling with embedded degree count
  const int CH = (2 * E + (NM + NC) - 1) / (NM + NC);
  pool_count_kernel<<<NM + NC, D, 0, stream>>>(tok_msg, ids_msg, poolM, NM, tok_con, ids_con, poolC,
                                               dst_cm, dst_mc, deg0, deg1, E, CH);

  // 3) scan (2 blocks) || weight+bias prep (2160 blocks)
  prepscan_kernel<<<2 + 15 * 144, 1024, 0, stream>>>(lin_W, kW, qW, vW, aW, a_rel, m_rel, p_rel,
                                                     kb, qb, vb, wbuf, bbuf,
                                                     deg0, off0, NM, deg1, off1, NC);

  // 4) initial linear (relu) || CSR scatter (z==2)
  {
    GemmP p0 = {poolM, wbuf, lin_b, nullptr, x0b, nullptr, nullptr, NM, D, D, 1};
    GemmP p1 = {poolC, wbuf + WSZ, lin_b + D, nullptr, x1b, nullptr, nullptr, NC, D, D, 1};
    gemm_bf16<<<dim3(mbMax, 3, 3), b256, 0, stream>>>(p0, p1, scAll);
  }
  // 5) layer 1: fused k|tq|vm projections, both node types
  {
    GemmP p0 = {x0b, wbuf + 2 * WSZ, bbuf, nullptr, projM1, nullptr, nullptr, NM, 1152, 1152, 0};
    GemmP p1 = {x1b, wbuf + 5 * WSZ, bbuf + 1152, nullptr, projC1, nullptr, nullptr, NC, 1152, 1152, 0};
    gemm_bf16<<<dim3(mbMax, 9, 2), b256, 0, stream>>>(p0, p1, scNone);
  }
  // 6) layer 1 attention, both edge types
  {
    AttnP a0 = {projC1, projM1 + 384, projC1 + 768, off0, el0, aggM, NM, 1152, 1152, 1152, (NM + 3) / 4};
    AttnP a1 = {projM1, projC1 + 384, projM1 + 768, off1, el1, aggC, NC, 1152, 1152, 1152, (NC + 3) / 4};
    attn_kernel<<<(NM + 3) / 4 + (NC + 3) / 4, b256, 0, stream>>>(a0, a1);
  }
  // 7) layer 1 a-proj + skip blend (bf16 xold)
  {
    GemmP p0 = {aggM, wbuf + 11 * WSZ, ab, nullptr, xn0b, x0b, skip + 0, NM, D, D, 0};
    GemmP p1 = {aggC, wbuf + 12 * WSZ, ab + D, nullptr, xn1b, x1b, skip + 1, NC, D, D, 0};
    gemm_bf16<<<dim3(mbMax, 3, 2), b256, 0, stream>>>(p0, p1, scNone);
  }
  // 8) layer 2 projections (M: tq only, N=384; C: k|vm, N=768)
  {
    GemmP p0 = {xn0b, wbuf + 8 * WSZ, bbuf + 2304, nullptr, projM2, nullptr, nullptr, NM, 384, 384, 0};
    GemmP p1 = {xn1b, wbuf + 9 * WSZ, bbuf + 2688, nullptr, projC2, nullptr, nullptr, NC, 768, 768, 0};
    gemm_bf16<<<dim3(mbMax, 6, 2), b256, 0, stream>>>(p0, p1, scNone);
  }
  // 9) layer 2 attention (edge type 0 only)
  {
    AttnP a0 = {projC2, projM2, projC2 + 384, off0, el0, aggM, NM, 768, 384, 768, (NM + 3) / 4};
    AttnP a1 = a0;
    attn_kernel<<<(NM + 3) / 4, b256, 0, stream>>>(a0, a1);
  }
  // 10) layer 2 a-proj -> d_out (f32), bf16 xold
  {
    GemmP p0 = {aggM, wbuf + 13 * WSZ, ab + 2 * D, (float*)d_out, nullptr, xn0b, skip + 2, NM, D, D, 0};
    GemmP p1 = p0;
    gemm_bf16<<<dim3(mbM, 3, 1), b256, 0, stream>>>(p0, p1, scNone);
  }
}